// Round 9
// baseline (174.180 us; speedup 1.0000x reference)
//
#include <hip/hip_runtime.h>
#include <stdint.h>

#define T_SEQ 2048
#define CDIM 1024
#define NHEAD 16
#define HS 64

typedef __bf16 bf16x8 __attribute__((ext_vector_type(8)));
typedef float f32x4 __attribute__((ext_vector_type(4)));
typedef short s16x4 __attribute__((ext_vector_type(4)));

__device__ __forceinline__ unsigned short f2bf(float f) {
  union { float f; unsigned u; } c; c.f = f;
  unsigned r = c.u + 0x7FFFu + ((c.u >> 16) & 1u);
  return (unsigned short)(r >> 16);
}

__device__ __forceinline__ void gload_lds16(const void* g, void* l) {
  __builtin_amdgcn_global_load_lds((__attribute__((address_space(1))) void*)(g),
                                   (__attribute__((address_space(3))) void*)(l),
                                   16, 0, 0);
}

// x fp32 [4096][1024] -> bf16 same layout. 4 elems/thread.
__global__ __launch_bounds__(256) void k_cvt_x(const float* __restrict__ x,
                                               unsigned short* __restrict__ xb) {
  int i = blockIdx.x * 256 + threadIdx.x;
  float4 f = reinterpret_cast<const float4*>(x)[i];
  ushort4 u;
  u.x = f2bf(f.x); u.y = f2bf(f.y); u.z = f2bf(f.z); u.w = f2bf(f.w);
  reinterpret_cast<ushort4*>(xb)[i] = u;
}

// W [K][N] fp32 -> Wt [N][K] bf16 (tiled transpose)
__global__ __launch_bounds__(256) void k_transpose(const float* __restrict__ W,
                                                   unsigned short* __restrict__ Wt,
                                                   int K, int N) {
  __shared__ float tile[32][33];
  int n0 = blockIdx.x * 32, k0 = blockIdx.y * 32;
  int c = threadIdx.x & 31, r0 = threadIdx.x >> 5;
#pragma unroll
  for (int r = r0; r < 32; r += 8) tile[r][c] = W[(size_t)(k0 + r) * N + n0 + c];
  __syncthreads();
#pragma unroll
  for (int r = r0; r < 32; r += 8) Wt[(size_t)(n0 + r) * K + k0 + c] = f2bf(tile[c][r]);
}

// C = A[M][KD] * Bt[N][KD]^T + bias. 128x128 tile, 4 waves, BK=32.
// MODE 0: qkv scatter epilogue (bf16, K pre-scaled by 1/sqrt(hs)*log2e).
// MODE 1: fp32 out.
template <int MODE, int KD>
__global__ __launch_bounds__(256) void k_gemm(const unsigned short* __restrict__ A,
                                              const unsigned short* __restrict__ Bt,
                                              const float* __restrict__ bias,
                                              float* __restrict__ outF,
                                              unsigned short* __restrict__ qb,
                                              unsigned short* __restrict__ kb,
                                              unsigned short* __restrict__ vb) {
  __shared__ __align__(16) unsigned short Al[128 * 32];
  __shared__ __align__(16) unsigned short Bl[128 * 32];
  const int tid = threadIdx.x;
  const int wave = tid >> 6, lane = tid & 63;
  const int m0 = blockIdx.x * 128, n0 = blockIdx.y * 128;
  const int wr = (wave >> 1) * 64, wc = (wave & 1) * 64;
  const int srow = tid >> 2, scol = (tid & 3) * 8;
  const int ka = (lane >> 4) * 8;
  f32x4 acc[4][4];
#pragma unroll
  for (int m = 0; m < 4; ++m)
#pragma unroll
    for (int n = 0; n < 4; ++n) acc[m][n] = f32x4{0.f, 0.f, 0.f, 0.f};

  for (int k0 = 0; k0 < KD; k0 += 32) {
#pragma unroll
    for (int r = 0; r < 2; ++r) {
      gload_lds16(A + (size_t)(m0 + r * 64 + srow) * KD + k0 + scol,
                  (char*)Al + r * 4096 + wave * 1024);
      gload_lds16(Bt + (size_t)(n0 + r * 64 + srow) * KD + k0 + scol,
                  (char*)Bl + r * 4096 + wave * 1024);
    }
    __syncthreads();
    bf16x8 af[4], bfr[4];
#pragma unroll
    for (int m = 0; m < 4; ++m)
      af[m] = *(const bf16x8*)&Al[(wr + m * 16 + (lane & 15)) * 32 + ka];
#pragma unroll
    for (int n = 0; n < 4; ++n)
      bfr[n] = *(const bf16x8*)&Bl[(wc + n * 16 + (lane & 15)) * 32 + ka];
#pragma unroll
    for (int m = 0; m < 4; ++m)
#pragma unroll
      for (int n = 0; n < 4; ++n)
        acc[m][n] = __builtin_amdgcn_mfma_f32_16x16x32_bf16(af[m], bfr[n], acc[m][n], 0, 0, 0);
    __syncthreads();
  }

#pragma unroll
  for (int m = 0; m < 4; ++m)
#pragma unroll
    for (int n = 0; n < 4; ++n)
#pragma unroll
      for (int j = 0; j < 4; ++j) {
        int row = m0 + wr + m * 16 + (lane >> 4) * 4 + j;
        int col = n0 + wc + n * 16 + (lane & 15);
        float v = acc[m][n][j] + bias[col];
        if (MODE == 1) {
          outF[(size_t)row * CDIM + col] = v;
        } else {
          int which = col >> 10;
          int h = (col >> 6) & 15;
          int d = col & 63;
          int b = row >> 11, t = row & (T_SEQ - 1);
          int bh = b * NHEAD + h;
          // Fold attention scale (1/sqrt(64) * log2e) into K.
          unsigned short bv = f2bf(which == 1 ? v * 0.18033688f : v);
          if (which == 0)      qb[((size_t)bh * T_SEQ + t) * HS + d] = bv;
          else if (which == 1) kb[((size_t)bh * T_SEQ + t) * HS + d] = bv;
          else                 vb[((size_t)bh * HS + d) * T_SEQ + t] = bv;
        }
      }
}

// Flash attention, causal-BALANCED + KV-split-3 + register PV.
// Block (192 thr = 3 waves) processes q-groups (63-p) then (p): total KV tiles
// = 33 for EVERY p -> all 1024 blocks run the same duration (R8's 10% occupancy
// was the starved tail of imbalanced blocks; capacity >= supply so "heavy
// first" never backfilled). Within a group the 3 waves split KV tiles
// (kt = wave, wave+3, ...), each with private online-softmax state; 3-way
// split-softmax merge via LDS runs twice per block TOTAL (not per iter).
// Swapped QK^T (mfma(K,Q)) -> lane-local softmax; cvt_pk-packed P is exactly
// the A-fragment of mfma_f32_16x16x16bf16_1k (validated R6), so PV runs from
// registers: no P LDS round-trip, no wave_barrier, no per-iter bank conflicts.
// K loaded at iter top (dead during softmax) -> live set ~135 VGPR, under the
// 170 cap of __launch_bounds__(192,3) (R4 lesson: cap must exceed live set).
// K pre-scaled by 1/sqrt(hs)*log2e in GEMM1 epilogue (log2-domain scores).
// q,k: [bh][t][64] bf16; v: [bh][64][t] bf16 (transposed); y: [4096][1024] bf16.
__global__ __launch_bounds__(192, 3) void k_attn(const unsigned short* __restrict__ qb,
                                                 const unsigned short* __restrict__ kb,
                                                 const unsigned short* __restrict__ vb,
                                                 unsigned short* __restrict__ yb) {
  __shared__ float Mo[3 * 32 * 64];     // per-wave partial O
  __shared__ float Lml[3][2][32];       // per-wave partial m, l
  // rid -> (xcd, bh, pair). 8 XCDs x 4 bh x 32 pairs = 1024 blocks.
  const int rid = blockIdx.x;
  const int xcd = rid & 7, i = rid >> 3;       // i in 0..127
  const int bh = xcd * 4 + (i & 3);
  const int p = i >> 2;                        // 0..31
  const int wave = threadIdx.x >> 6;           // 0..2
  const int lane = threadIdx.x & 63;
  const int l15 = lane & 15, lh = lane >> 4;
  const unsigned short* qh = qb + (size_t)bh * T_SEQ * HS;
  const unsigned short* kh = kb + (size_t)bh * T_SEQ * HS;
  const unsigned short* vh = vb + (size_t)bh * HS * T_SEQ;
  const int b = bh >> 4, h = bh & 15;

  for (int grp = 0; grp < 2; ++grp) {
    const int g = grp ? p : 63 - p;
    const int q0 = g * 32;
    const int nkt = (q0 >> 6) + 1;

    bf16x8 qf[2][2];
#pragma unroll
    for (int np = 0; np < 2; ++np)
#pragma unroll
      for (int kk = 0; kk < 2; ++kk)
        qf[np][kk] = *(const bf16x8*)&qh[(size_t)(q0 + np * 16 + l15) * HS + kk * 32 + lh * 8];

    f32x4 o[2][4];               // PV layout: q = m*16 + lh*4 + j, d = n*16 + l15
    float Mx[2], Ls[2];          // softmax layout: q = np*16 + l15
#pragma unroll
    for (int m = 0; m < 2; ++m) {
#pragma unroll
      for (int n = 0; n < 4; ++n) o[m][n] = f32x4{0.f, 0.f, 0.f, 0.f};
      Mx[m] = -INFINITY; Ls[m] = 0.f;
    }

    for (int kt = wave; kt < nkt; kt += 3) {
      const int kvb = kt * 64;
      // K fragments for QK^T (dead after the MFMAs -> not live in softmax)
      bf16x8 kf[4][2];
#pragma unroll
      for (int n = 0; n < 4; ++n)
#pragma unroll
        for (int kk = 0; kk < 2; ++kk)
          kf[n][kk] = *(const bf16x8*)&kh[(size_t)(kvb + n * 16 + l15) * HS + kk * 32 + lh * 8];
      // V fragments for 16x16x16 PV (issued now, consumed after softmax)
      s16x4 v4[4][4];
#pragma unroll
      for (int n = 0; n < 4; ++n)
#pragma unroll
        for (int mp = 0; mp < 4; ++mp)
          v4[n][mp] = *(const s16x4*)&vh[(size_t)(n * 16 + l15) * T_SEQ + kvb + mp * 16 + lh * 4];

      // Swapped QK^T: s2[np][mp] -> q = np*16+l15, k = kvb+mp*16+lh*4+j
      f32x4 s2[2][4];
#pragma unroll
      for (int np = 0; np < 2; ++np)
#pragma unroll
        for (int mp = 0; mp < 4; ++mp) {
          f32x4 z = f32x4{0.f, 0.f, 0.f, 0.f};
          z = __builtin_amdgcn_mfma_f32_16x16x32_bf16(kf[mp][0], qf[np][0], z, 0, 0, 0);
          z = __builtin_amdgcn_mfma_f32_16x16x32_bf16(kf[mp][1], qf[np][1], z, 0, 0, 0);
          s2[np][mp] = z;
        }

      const bool diag = (kvb + 63 > q0);
      float alpha_sm[2];
      s16x4 w4[2][4];
#pragma unroll
      for (int np = 0; np < 2; ++np) {
        const int qg = q0 + np * 16 + l15;
        if (diag) {
#pragma unroll
          for (int mp = 0; mp < 4; ++mp)
#pragma unroll
            for (int j = 0; j < 4; ++j)
              if (kvb + mp * 16 + lh * 4 + j > qg) s2[np][mp][j] = -3.0e38f;
        }
        f32x4 t01, t23, t;
#pragma unroll
        for (int e = 0; e < 4; ++e) {
          t01[e] = fmaxf(s2[np][0][e], s2[np][1][e]);
          t23[e] = fmaxf(s2[np][2][e], s2[np][3][e]);
          t[e] = fmaxf(t01[e], t23[e]);
        }
        float mx = fmaxf(fmaxf(t[0], t[1]), fmaxf(t[2], t[3]));
        mx = fmaxf(mx, __shfl_xor(mx, 16));
        mx = fmaxf(mx, __shfl_xor(mx, 32));
        const float newM = fmaxf(Mx[np], mx);
        alpha_sm[np] = __builtin_exp2f(Mx[np] - newM);
        Mx[np] = newM;
        float rs = 0.f;
#pragma unroll
        for (int mp = 0; mp < 4; ++mp) {
          float p0 = __builtin_exp2f(s2[np][mp][0] - newM);
          float p1 = __builtin_exp2f(s2[np][mp][1] - newM);
          float p2 = __builtin_exp2f(s2[np][mp][2] - newM);
          float p3 = __builtin_exp2f(s2[np][mp][3] - newM);
          rs += (p0 + p1) + (p2 + p3);
          unsigned lo, hi;
          asm("v_cvt_pk_bf16_f32 %0, %1, %2" : "=v"(lo) : "v"(p0), "v"(p1));
          asm("v_cvt_pk_bf16_f32 %0, %1, %2" : "=v"(hi) : "v"(p2), "v"(p3));
          union { unsigned u[2]; s16x4 s; } cv;
          cv.u[0] = lo; cv.u[1] = hi;
          w4[np][mp] = cv.s;
        }
        rs += __shfl_xor(rs, 16);
        rs += __shfl_xor(rs, 32);
        Ls[np] = Ls[np] * alpha_sm[np] + rs;
      }

      // broadcast alpha to PV layout and rescale o
#pragma unroll
      for (int m = 0; m < 2; ++m)
#pragma unroll
        for (int j = 0; j < 4; ++j) {
          const float a = __shfl(alpha_sm[m], lh * 4 + j, 16);
#pragma unroll
          for (int n = 0; n < 4; ++n) o[m][n][j] *= a;
        }

      // PV from registers: o[m][n] += P(np=m) * V, 16x16x16 MFMA
#pragma unroll
      for (int m = 0; m < 2; ++m)
#pragma unroll
        for (int n = 0; n < 4; ++n)
#pragma unroll
          for (int mp = 0; mp < 4; ++mp)
            o[m][n] = __builtin_amdgcn_mfma_f32_16x16x16bf16_1k(w4[m][mp], v4[n][mp], o[m][n], 0, 0, 0);
    }

    // ---- publish partials ----
    if (lh == 0) {
#pragma unroll
      for (int np = 0; np < 2; ++np) {
        Lml[wave][0][np * 16 + l15] = Mx[np];
        Lml[wave][1][np * 16 + l15] = Ls[np];
      }
    }
#pragma unroll
    for (int m = 0; m < 2; ++m)
#pragma unroll
      for (int j = 0; j < 4; ++j)
#pragma unroll
        for (int n = 0; n < 4; ++n)
          Mo[wave * 2048 + (m * 16 + lh * 4 + j) * 64 + n * 16 + l15] = o[m][n][j];
    __syncthreads();

    // ---- distributed 3-way merge + store: 256 chunks of 8 cols ----
    for (int c = threadIdx.x; c < 256; c += 192) {
      const int rl = c >> 3, c0 = (c & 7) * 8;
      const float m0 = Lml[0][0][rl], m1 = Lml[1][0][rl], m2 = Lml[2][0][rl];
      const float l0 = Lml[0][1][rl], l1 = Lml[1][1][rl], l2 = Lml[2][1][rl];
      const float M = fmaxf(fmaxf(m0, m1), m2);
      const float a0 = __builtin_exp2f(m0 - M);
      const float a1 = __builtin_exp2f(m1 - M);
      const float a2 = __builtin_exp2f(m2 - M);
      const float inv = 1.0f / (a0 * l0 + a1 * l1 + a2 * l2);
      const float* O0 = &Mo[rl * 64 + c0];
      const float* O1 = O0 + 2048;
      const float* O2 = O0 + 4096;
      unsigned pk[4];
#pragma unroll
      for (int e = 0; e < 4; ++e) {
        float va = (a0 * O0[2 * e] + a1 * O1[2 * e] + a2 * O2[2 * e]) * inv;
        float vb2 = (a0 * O0[2 * e + 1] + a1 * O1[2 * e + 1] + a2 * O2[2 * e + 1]) * inv;
        pk[e] = (unsigned)f2bf(va) | ((unsigned)f2bf(vb2) << 16);
      }
      uint4 u; u.x = pk[0]; u.y = pk[1]; u.z = pk[2]; u.w = pk[3];
      *(uint4*)&yb[(size_t)(b * T_SEQ + q0 + rl) * CDIM + h * 64 + c0] = u;
    }
    __syncthreads();
  }
}

extern "C" void kernel_launch(void* const* d_in, const int* in_sizes, int n_in,
                              void* d_out, int out_size, void* d_ws, size_t ws_size,
                              hipStream_t stream) {
  (void)in_sizes; (void)n_in; (void)out_size; (void)ws_size;
  const float* x      = (const float*)d_in[0];
  const float* W_attn = (const float*)d_in[1];
  const float* b_attn = (const float*)d_in[2];
  const float* W_proj = (const float*)d_in[3];
  const float* b_proj = (const float*)d_in[4];
  float* out = (float*)d_out;
  char* ws = (char*)d_ws;

  unsigned short* xb  = (unsigned short*)(ws);              //  8 MiB [4096][1024]
  unsigned short* Wta = (unsigned short*)(ws + 8388608);    //  6 MiB [3072][1024]
  unsigned short* Wtp = (unsigned short*)(ws + 14680064);   //  2 MiB [1024][1024]
  unsigned short* qbf = (unsigned short*)(ws + 16777216);   //  8 MiB [32][2048][64]
  unsigned short* kbf = (unsigned short*)(ws + 25165824);   //  8 MiB [32][2048][64]
  unsigned short* vbf = (unsigned short*)(ws + 33554432);   //  8 MiB [32][64][2048]
  unsigned short* ybf = (unsigned short*)(ws + 41943040);   //  8 MiB [4096][1024]

  k_cvt_x<<<4096, 256, 0, stream>>>(x, xb);
  k_transpose<<<dim3(96, 32), 256, 0, stream>>>(W_attn, Wta, 1024, 3072);
  k_transpose<<<dim3(32, 32), 256, 0, stream>>>(W_proj, Wtp, 1024, 1024);
  k_gemm<0, 1024><<<dim3(32, 24), 256, 0, stream>>>(xb, Wta, b_attn, nullptr, qbf, kbf, vbf);
  k_attn<<<1024, 192, 0, stream>>>(qbf, kbf, vbf, ybf);
  k_gemm<1, 1024><<<dim3(32, 8), 256, 0, stream>>>(ybf, Wtp, b_proj, out, nullptr, nullptr, nullptr);
}

// Round 10
// 172.333 us; speedup vs baseline: 1.0107x; 1.0107x over previous
//
#include <hip/hip_runtime.h>
#include <stdint.h>

#define T_SEQ 2048
#define CDIM 1024
#define NHEAD 16
#define HS 64

typedef __bf16 bf16x8 __attribute__((ext_vector_type(8)));
typedef float f32x4 __attribute__((ext_vector_type(4)));

__device__ __forceinline__ unsigned short f2bf(float f) {
  union { float f; unsigned u; } c; c.f = f;
  unsigned r = c.u + 0x7FFFu + ((c.u >> 16) & 1u);
  return (unsigned short)(r >> 16);
}

__device__ __forceinline__ void gload_lds16(const void* g, void* l) {
  __builtin_amdgcn_global_load_lds((__attribute__((address_space(1))) void*)(g),
                                   (__attribute__((address_space(3))) void*)(l),
                                   16, 0, 0);
}

// x fp32 [4096][1024] -> bf16 same layout. 4 elems/thread.
__global__ __launch_bounds__(256) void k_cvt_x(const float* __restrict__ x,
                                               unsigned short* __restrict__ xb) {
  int i = blockIdx.x * 256 + threadIdx.x;
  float4 f = reinterpret_cast<const float4*>(x)[i];
  ushort4 u;
  u.x = f2bf(f.x); u.y = f2bf(f.y); u.z = f2bf(f.z); u.w = f2bf(f.w);
  reinterpret_cast<ushort4*>(xb)[i] = u;
}

// W [K][N] fp32 -> Wt [N][K] bf16 (tiled transpose)
__global__ __launch_bounds__(256) void k_transpose(const float* __restrict__ W,
                                                   unsigned short* __restrict__ Wt,
                                                   int K, int N) {
  __shared__ float tile[32][33];
  int n0 = blockIdx.x * 32, k0 = blockIdx.y * 32;
  int c = threadIdx.x & 31, r0 = threadIdx.x >> 5;
#pragma unroll
  for (int r = r0; r < 32; r += 8) tile[r][c] = W[(size_t)(k0 + r) * N + n0 + c];
  __syncthreads();
#pragma unroll
  for (int r = r0; r < 32; r += 8) Wt[(size_t)(n0 + r) * K + k0 + c] = f2bf(tile[c][r]);
}

// C = A[M][KD] * Bt[N][KD]^T + bias. 128x128 tile, 4 waves, BK=32.
// MODE 0: qkv scatter epilogue (bf16, K pre-scaled by 1/sqrt(hs)*log2e).
// MODE 1: fp32 out.
template <int MODE, int KD>
__global__ __launch_bounds__(256) void k_gemm(const unsigned short* __restrict__ A,
                                              const unsigned short* __restrict__ Bt,
                                              const float* __restrict__ bias,
                                              float* __restrict__ outF,
                                              unsigned short* __restrict__ qb,
                                              unsigned short* __restrict__ kb,
                                              unsigned short* __restrict__ vb) {
  __shared__ __align__(16) unsigned short Al[128 * 32];
  __shared__ __align__(16) unsigned short Bl[128 * 32];
  const int tid = threadIdx.x;
  const int wave = tid >> 6, lane = tid & 63;
  const int m0 = blockIdx.x * 128, n0 = blockIdx.y * 128;
  const int wr = (wave >> 1) * 64, wc = (wave & 1) * 64;
  const int srow = tid >> 2, scol = (tid & 3) * 8;
  const int ka = (lane >> 4) * 8;
  f32x4 acc[4][4];
#pragma unroll
  for (int m = 0; m < 4; ++m)
#pragma unroll
    for (int n = 0; n < 4; ++n) acc[m][n] = f32x4{0.f, 0.f, 0.f, 0.f};

  for (int k0 = 0; k0 < KD; k0 += 32) {
#pragma unroll
    for (int r = 0; r < 2; ++r) {
      gload_lds16(A + (size_t)(m0 + r * 64 + srow) * KD + k0 + scol,
                  (char*)Al + r * 4096 + wave * 1024);
      gload_lds16(Bt + (size_t)(n0 + r * 64 + srow) * KD + k0 + scol,
                  (char*)Bl + r * 4096 + wave * 1024);
    }
    __syncthreads();
    bf16x8 af[4], bfr[4];
#pragma unroll
    for (int m = 0; m < 4; ++m)
      af[m] = *(const bf16x8*)&Al[(wr + m * 16 + (lane & 15)) * 32 + ka];
#pragma unroll
    for (int n = 0; n < 4; ++n)
      bfr[n] = *(const bf16x8*)&Bl[(wc + n * 16 + (lane & 15)) * 32 + ka];
#pragma unroll
    for (int m = 0; m < 4; ++m)
#pragma unroll
      for (int n = 0; n < 4; ++n)
        acc[m][n] = __builtin_amdgcn_mfma_f32_16x16x32_bf16(af[m], bfr[n], acc[m][n], 0, 0, 0);
    __syncthreads();
  }

#pragma unroll
  for (int m = 0; m < 4; ++m)
#pragma unroll
    for (int n = 0; n < 4; ++n)
#pragma unroll
      for (int j = 0; j < 4; ++j) {
        int row = m0 + wr + m * 16 + (lane >> 4) * 4 + j;
        int col = n0 + wc + n * 16 + (lane & 15);
        float v = acc[m][n][j] + bias[col];
        if (MODE == 1) {
          outF[(size_t)row * CDIM + col] = v;
        } else {
          int which = col >> 10;
          int h = (col >> 6) & 15;
          int d = col & 63;
          int b = row >> 11, t = row & (T_SEQ - 1);
          int bh = b * NHEAD + h;
          // Fold attention scale (1/sqrt(64) * log2e) into K.
          unsigned short bv = f2bf(which == 1 ? v * 0.18033688f : v);
          if (which == 0)      qb[((size_t)bh * T_SEQ + t) * HS + d] = bv;
          else if (which == 1) kb[((size_t)bh * T_SEQ + t) * HS + d] = bv;
          else                 vb[((size_t)bh * HS + d) * T_SEQ + t] = bv;
        }
      }
}

// Flash attention: causal-BALANCED pairs + KV-split-3 + R8 per-wave structure.
// Block (3 waves) does q-group (63-p) then (p): 33 KV tiles for every p ->
// all 1024 blocks finish together (R9's balancing, kept). Waves split each
// group's KV tiles (kt = wave, wave+3, ...) with private online-softmax state;
// two LDS merges per block TOTAL. Per-wave microstructure is R8's proven one:
// swapped QK^T -> lane-local softmax, cvt_pk P -> padded LDS (PSTR 72,
// 2-way=free), PV = 16x16x32 MFMA with bf16x8 V^T fragments (8x16B loads).
// R9 regression root-caused: __launch_bounds__(192,3) made the allocator
// optimize for an 84-VGPR budget, serializing loads (VALUBusy 38->24%).
// Plain __launch_bounds__(192) restores the ~132-VGPR schedule = 3 waves/SIMD
// capacity, exactly matching the 3072-wave supply (4 blocks/CU co-resident).
// P-buffers (13.8KB) overlay the merge buffer Mo (lifetimes disjoint).
// K pre-scaled by 1/sqrt(hs)*log2e in GEMM1 epilogue (log2-domain scores).
// q,k: [bh][t][64] bf16; v: [bh][64][t] bf16 (transposed); y: [4096][1024] bf16.
#define PSTR 72
#define LOSTR 65
__global__ __launch_bounds__(192) void k_attn(const unsigned short* __restrict__ qb,
                                              const unsigned short* __restrict__ kb,
                                              const unsigned short* __restrict__ vb,
                                              unsigned short* __restrict__ yb) {
  __shared__ __align__(16) char pool[3 * 32 * LOSTR * 4];  // 24960 B
  __shared__ float Lml[3][2][32];
  unsigned short* Pl = (unsigned short*)pool;   // [3][32*PSTR] during K-loop
  float* Mo = (float*)pool;                     // [3][32*LOSTR] at merge (overlay)
  // rid -> (xcd, bh, pair). 8 XCDs x 4 bh x 32 pairs = 1024 blocks.
  const int rid = blockIdx.x;
  const int xcd = rid & 7, i = rid >> 3;       // i in 0..127
  const int bh = xcd * 4 + (i & 3);
  const int p = i >> 2;                        // 0..31
  const int wave = threadIdx.x >> 6;           // 0..2
  const int lane = threadIdx.x & 63;
  const int l15 = lane & 15, lh = lane >> 4;
  const unsigned short* qh = qb + (size_t)bh * T_SEQ * HS;
  const unsigned short* kh = kb + (size_t)bh * T_SEQ * HS;
  const unsigned short* vh = vb + (size_t)bh * HS * T_SEQ;
  const int b = bh >> 4, h = bh & 15;
  unsigned short* Pw = Pl + wave * 32 * PSTR;

  for (int grp = 0; grp < 2; ++grp) {
    const int g = grp ? p : 63 - p;
    const int q0 = g * 32;
    const int nkt = (q0 >> 6) + 1;

    bf16x8 qf[2][2];
#pragma unroll
    for (int np = 0; np < 2; ++np)
#pragma unroll
      for (int kk = 0; kk < 2; ++kk)
        qf[np][kk] = *(const bf16x8*)&qh[(size_t)(q0 + np * 16 + l15) * HS + kk * 32 + lh * 8];

    f32x4 o[2][4];               // PV layout: q = m*16 + lh*4 + j, d = n*16 + l15
    float Mx[2], Ls[2];          // softmax layout: q = np*16 + l15
#pragma unroll
    for (int m = 0; m < 2; ++m) {
#pragma unroll
      for (int n = 0; n < 4; ++n) o[m][n] = f32x4{0.f, 0.f, 0.f, 0.f};
      Mx[m] = -INFINITY; Ls[m] = 0.f;
    }

    bf16x8 kf[4][2], vf[4][2];
    // prologue: K fragments of this wave's first tile (rows <= 191, in-bounds)
#pragma unroll
    for (int n = 0; n < 4; ++n)
#pragma unroll
      for (int kk = 0; kk < 2; ++kk)
        kf[n][kk] = *(const bf16x8*)&kh[(size_t)(wave * 64 + n * 16 + l15) * HS + kk * 32 + lh * 8];

    for (int kt = wave; kt < nkt; kt += 3) {
      const int kvb = kt * 64;
      // V fragments for THIS tile (consumed after softmax -> latency hidden)
#pragma unroll
      for (int n = 0; n < 4; ++n)
#pragma unroll
        for (int kk = 0; kk < 2; ++kk)
          vf[n][kk] = *(const bf16x8*)&vh[(size_t)(n * 16 + l15) * T_SEQ + kvb + kk * 32 + lh * 8];

      // Swapped QK^T: s2[np][mp] -> q = np*16+l15, k = kvb+mp*16+lh*4+j
      f32x4 s2[2][4];
#pragma unroll
      for (int np = 0; np < 2; ++np)
#pragma unroll
        for (int mp = 0; mp < 4; ++mp) {
          f32x4 z = f32x4{0.f, 0.f, 0.f, 0.f};
          z = __builtin_amdgcn_mfma_f32_16x16x32_bf16(kf[mp][0], qf[np][0], z, 0, 0, 0);
          z = __builtin_amdgcn_mfma_f32_16x16x32_bf16(kf[mp][1], qf[np][1], z, 0, 0, 0);
          s2[np][mp] = z;
        }

      // K fragments for THIS WAVE'S NEXT tile (kt+3): old kf dead after MFMAs.
      if (kt + 3 < nkt) {
        const int kvb2 = kvb + 192;
#pragma unroll
        for (int n = 0; n < 4; ++n)
#pragma unroll
          for (int kk = 0; kk < 2; ++kk)
            kf[n][kk] = *(const bf16x8*)&kh[(size_t)(kvb2 + n * 16 + l15) * HS + kk * 32 + lh * 8];
      }

      const bool diag = (kvb + 63 > q0);
      float alpha_sm[2];
#pragma unroll
      for (int np = 0; np < 2; ++np) {
        const int qg = q0 + np * 16 + l15;
        if (diag) {
#pragma unroll
          for (int mp = 0; mp < 4; ++mp)
#pragma unroll
            for (int j = 0; j < 4; ++j)
              if (kvb + mp * 16 + lh * 4 + j > qg) s2[np][mp][j] = -3.0e38f;
        }
        // in-register row max (full ILP) + 2-shfl cross-quadrant reduce
        f32x4 t01, t23, t;
#pragma unroll
        for (int e = 0; e < 4; ++e) {
          t01[e] = fmaxf(s2[np][0][e], s2[np][1][e]);
          t23[e] = fmaxf(s2[np][2][e], s2[np][3][e]);
          t[e] = fmaxf(t01[e], t23[e]);
        }
        float mx = fmaxf(fmaxf(t[0], t[1]), fmaxf(t[2], t[3]));
        mx = fmaxf(mx, __shfl_xor(mx, 16));
        mx = fmaxf(mx, __shfl_xor(mx, 32));
        const float newM = fmaxf(Mx[np], mx);
        alpha_sm[np] = __builtin_exp2f(Mx[np] - newM);
        Mx[np] = newM;
        float rs = 0.f;
        uint2 w[4];
#pragma unroll
        for (int mp = 0; mp < 4; ++mp) {
          float p0 = __builtin_exp2f(s2[np][mp][0] - newM);
          float p1 = __builtin_exp2f(s2[np][mp][1] - newM);
          float p2 = __builtin_exp2f(s2[np][mp][2] - newM);
          float p3 = __builtin_exp2f(s2[np][mp][3] - newM);
          rs += (p0 + p1) + (p2 + p3);
          unsigned lo, hi;
          asm("v_cvt_pk_bf16_f32 %0, %1, %2" : "=v"(lo) : "v"(p0), "v"(p1));
          asm("v_cvt_pk_bf16_f32 %0, %1, %2" : "=v"(hi) : "v"(p2), "v"(p3));
          w[mp].x = lo; w[mp].y = hi;
        }
        rs += __shfl_xor(rs, 16);
        rs += __shfl_xor(rs, 32);
        Ls[np] = Ls[np] * alpha_sm[np] + rs;
#pragma unroll
        for (int mp = 0; mp < 4; ++mp)
          *(uint2*)&Pw[(np * 16 + l15) * PSTR + mp * 16 + lh * 4] = w[mp];
      }

      // broadcast alpha to PV layout and rescale o
#pragma unroll
      for (int m = 0; m < 2; ++m)
#pragma unroll
        for (int j = 0; j < 4; ++j) {
          const float a = __shfl(alpha_sm[m], lh * 4 + j, 16);
#pragma unroll
          for (int n = 0; n < 4; ++n) o[m][n][j] *= a;
        }

      __builtin_amdgcn_wave_barrier();  // keep ds_writes above the reads below

      bf16x8 pf[2][2];
#pragma unroll
      for (int m = 0; m < 2; ++m)
#pragma unroll
        for (int kk = 0; kk < 2; ++kk)
          pf[m][kk] = *(const bf16x8*)&Pw[(m * 16 + l15) * PSTR + kk * 32 + lh * 8];

#pragma unroll
      for (int m = 0; m < 2; ++m)
#pragma unroll
        for (int n = 0; n < 4; ++n) {
          o[m][n] = __builtin_amdgcn_mfma_f32_16x16x32_bf16(pf[m][0], vf[n][0], o[m][n], 0, 0, 0);
          o[m][n] = __builtin_amdgcn_mfma_f32_16x16x32_bf16(pf[m][1], vf[n][1], o[m][n], 0, 0, 0);
        }
    }

    // ---- publish partials (Mo overlays Pl; ensure all waves' pf reads done) ----
    __syncthreads();
    if (lh == 0) {
#pragma unroll
      for (int np = 0; np < 2; ++np) {
        Lml[wave][0][np * 16 + l15] = Mx[np];
        Lml[wave][1][np * 16 + l15] = Ls[np];
      }
    }
#pragma unroll
    for (int m = 0; m < 2; ++m)
#pragma unroll
      for (int j = 0; j < 4; ++j)
#pragma unroll
        for (int n = 0; n < 4; ++n)
          Mo[wave * 32 * LOSTR + (m * 16 + lh * 4 + j) * LOSTR + n * 16 + l15] = o[m][n][j];
    __syncthreads();

    // ---- distributed 3-way merge + store: 256 chunks of 8 cols ----
    for (int c = threadIdx.x; c < 256; c += 192) {
      const int rl = c >> 3, c0 = (c & 7) * 8;
      const float m0 = Lml[0][0][rl], m1 = Lml[1][0][rl], m2 = Lml[2][0][rl];
      const float l0 = Lml[0][1][rl], l1 = Lml[1][1][rl], l2 = Lml[2][1][rl];
      const float M = fmaxf(fmaxf(m0, m1), m2);
      const float a0 = __builtin_exp2f(m0 - M);
      const float a1 = __builtin_exp2f(m1 - M);
      const float a2 = __builtin_exp2f(m2 - M);
      const float inv = 1.0f / (a0 * l0 + a1 * l1 + a2 * l2);
      const float* O0 = &Mo[rl * LOSTR + c0];
      const float* O1 = O0 + 32 * LOSTR;
      const float* O2 = O0 + 64 * LOSTR;
      unsigned pk[4];
#pragma unroll
      for (int e = 0; e < 4; ++e) {
        float va = (a0 * O0[2 * e] + a1 * O1[2 * e] + a2 * O2[2 * e]) * inv;
        float vb2 = (a0 * O0[2 * e + 1] + a1 * O1[2 * e + 1] + a2 * O2[2 * e + 1]) * inv;
        pk[e] = (unsigned)f2bf(va) | ((unsigned)f2bf(vb2) << 16);
      }
      uint4 u; u.x = pk[0]; u.y = pk[1]; u.z = pk[2]; u.w = pk[3];
      *(uint4*)&yb[(size_t)(b * T_SEQ + q0 + rl) * CDIM + h * 64 + c0] = u;
    }
    __syncthreads();  // protect Pl reuse in next group against merge reads
  }
}

extern "C" void kernel_launch(void* const* d_in, const int* in_sizes, int n_in,
                              void* d_out, int out_size, void* d_ws, size_t ws_size,
                              hipStream_t stream) {
  (void)in_sizes; (void)n_in; (void)out_size; (void)ws_size;
  const float* x      = (const float*)d_in[0];
  const float* W_attn = (const float*)d_in[1];
  const float* b_attn = (const float*)d_in[2];
  const float* W_proj = (const float*)d_in[3];
  const float* b_proj = (const float*)d_in[4];
  float* out = (float*)d_out;
  char* ws = (char*)d_ws;

  unsigned short* xb  = (unsigned short*)(ws);              //  8 MiB [4096][1024]
  unsigned short* Wta = (unsigned short*)(ws + 8388608);    //  6 MiB [3072][1024]
  unsigned short* Wtp = (unsigned short*)(ws + 14680064);   //  2 MiB [1024][1024]
  unsigned short* qbf = (unsigned short*)(ws + 16777216);   //  8 MiB [32][2048][64]
  unsigned short* kbf = (unsigned short*)(ws + 25165824);   //  8 MiB [32][2048][64]
  unsigned short* vbf = (unsigned short*)(ws + 33554432);   //  8 MiB [32][64][2048]
  unsigned short* ybf = (unsigned short*)(ws + 41943040);   //  8 MiB [4096][1024]

  k_cvt_x<<<4096, 256, 0, stream>>>(x, xb);
  k_transpose<<<dim3(96, 32), 256, 0, stream>>>(W_attn, Wta, 1024, 3072);
  k_transpose<<<dim3(32, 32), 256, 0, stream>>>(W_proj, Wtp, 1024, 1024);
  k_gemm<0, 1024><<<dim3(32, 24), 256, 0, stream>>>(xb, Wta, b_attn, nullptr, qbf, kbf, vbf);
  k_attn<<<1024, 192, 0, stream>>>(qbf, kbf, vbf, ybf);
  k_gemm<1, 1024><<<dim3(32, 8), 256, 0, stream>>>(ybf, Wtp, b_proj, out, nullptr, nullptr, nullptr);
}

// Round 11
// 148.740 us; speedup vs baseline: 1.1710x; 1.1586x over previous
//
#include <hip/hip_runtime.h>
#include <stdint.h>

#define T_SEQ 2048
#define CDIM 1024
#define NHEAD 16
#define HS 64

typedef __bf16 bf16x8 __attribute__((ext_vector_type(8)));
typedef float f32x4 __attribute__((ext_vector_type(4)));
typedef float f32x16 __attribute__((ext_vector_type(16)));

__device__ __forceinline__ unsigned short f2bf(float f) {
  union { float f; unsigned u; } c; c.f = f;
  unsigned r = c.u + 0x7FFFu + ((c.u >> 16) & 1u);
  return (unsigned short)(r >> 16);
}

__device__ __forceinline__ void gload_lds16(const void* g, void* l) {
  __builtin_amdgcn_global_load_lds((__attribute__((address_space(1))) void*)(g),
                                   (__attribute__((address_space(3))) void*)(l),
                                   16, 0, 0);
}

// x fp32 [4096][1024] -> bf16 same layout. 4 elems/thread.
__global__ __launch_bounds__(256) void k_cvt_x(const float* __restrict__ x,
                                               unsigned short* __restrict__ xb) {
  int i = blockIdx.x * 256 + threadIdx.x;
  float4 f = reinterpret_cast<const float4*>(x)[i];
  ushort4 u;
  u.x = f2bf(f.x); u.y = f2bf(f.y); u.z = f2bf(f.z); u.w = f2bf(f.w);
  reinterpret_cast<ushort4*>(xb)[i] = u;
}

// W [K][N] fp32 -> Wt [N][K] bf16 (tiled transpose)
__global__ __launch_bounds__(256) void k_transpose(const float* __restrict__ W,
                                                   unsigned short* __restrict__ Wt,
                                                   int K, int N) {
  __shared__ float tile[32][33];
  int n0 = blockIdx.x * 32, k0 = blockIdx.y * 32;
  int c = threadIdx.x & 31, r0 = threadIdx.x >> 5;
#pragma unroll
  for (int r = r0; r < 32; r += 8) tile[r][c] = W[(size_t)(k0 + r) * N + n0 + c];
  __syncthreads();
#pragma unroll
  for (int r = r0; r < 32; r += 8) Wt[(size_t)(n0 + r) * K + k0 + c] = f2bf(tile[c][r]);
}

// C = A[M][KD] * Bt[N][KD]^T + bias. 128x128 tile, 4 waves, BK=32.
// MODE 0: qkv scatter epilogue (bf16, K pre-scaled by 1/sqrt(hs)*log2e).
// MODE 1: fp32 out.
template <int MODE, int KD>
__global__ __launch_bounds__(256) void k_gemm(const unsigned short* __restrict__ A,
                                              const unsigned short* __restrict__ Bt,
                                              const float* __restrict__ bias,
                                              float* __restrict__ outF,
                                              unsigned short* __restrict__ qb,
                                              unsigned short* __restrict__ kb,
                                              unsigned short* __restrict__ vb) {
  __shared__ __align__(16) unsigned short Al[128 * 32];
  __shared__ __align__(16) unsigned short Bl[128 * 32];
  const int tid = threadIdx.x;
  const int wave = tid >> 6, lane = tid & 63;
  const int m0 = blockIdx.x * 128, n0 = blockIdx.y * 128;
  const int wr = (wave >> 1) * 64, wc = (wave & 1) * 64;
  const int srow = tid >> 2, scol = (tid & 3) * 8;
  const int ka = (lane >> 4) * 8;
  f32x4 acc[4][4];
#pragma unroll
  for (int m = 0; m < 4; ++m)
#pragma unroll
    for (int n = 0; n < 4; ++n) acc[m][n] = f32x4{0.f, 0.f, 0.f, 0.f};

  for (int k0 = 0; k0 < KD; k0 += 32) {
#pragma unroll
    for (int r = 0; r < 2; ++r) {
      gload_lds16(A + (size_t)(m0 + r * 64 + srow) * KD + k0 + scol,
                  (char*)Al + r * 4096 + wave * 1024);
      gload_lds16(Bt + (size_t)(n0 + r * 64 + srow) * KD + k0 + scol,
                  (char*)Bl + r * 4096 + wave * 1024);
    }
    __syncthreads();
    bf16x8 af[4], bfr[4];
#pragma unroll
    for (int m = 0; m < 4; ++m)
      af[m] = *(const bf16x8*)&Al[(wr + m * 16 + (lane & 15)) * 32 + ka];
#pragma unroll
    for (int n = 0; n < 4; ++n)
      bfr[n] = *(const bf16x8*)&Bl[(wc + n * 16 + (lane & 15)) * 32 + ka];
#pragma unroll
    for (int m = 0; m < 4; ++m)
#pragma unroll
      for (int n = 0; n < 4; ++n)
        acc[m][n] = __builtin_amdgcn_mfma_f32_16x16x32_bf16(af[m], bfr[n], acc[m][n], 0, 0, 0);
    __syncthreads();
  }

#pragma unroll
  for (int m = 0; m < 4; ++m)
#pragma unroll
    for (int n = 0; n < 4; ++n)
#pragma unroll
      for (int j = 0; j < 4; ++j) {
        int row = m0 + wr + m * 16 + (lane >> 4) * 4 + j;
        int col = n0 + wc + n * 16 + (lane & 15);
        float v = acc[m][n][j] + bias[col];
        if (MODE == 1) {
          outF[(size_t)row * CDIM + col] = v;
        } else {
          int which = col >> 10;
          int h = (col >> 6) & 15;
          int d = col & 63;
          int b = row >> 11, t = row & (T_SEQ - 1);
          int bh = b * NHEAD + h;
          // Fold attention scale (1/sqrt(64) * log2e) into K.
          unsigned short bv = f2bf(which == 1 ? v * 0.18033688f : v);
          if (which == 0)      qb[((size_t)bh * T_SEQ + t) * HS + d] = bv;
          else if (which == 1) kb[((size_t)bh * T_SEQ + t) * HS + d] = bv;
          else                 vb[((size_t)bh * HS + d) * T_SEQ + t] = bv;
        }
      }
}

// Flash attention: 32x32-MFMA swapped-QK with FULLY lane-local softmax.
// S^T = mfma_32x32x16(A=K, B=Q^T): lane holds 32 of 64 key-scores for ONE
// q-row (col=l&31=q; row=(reg&3)+8*(reg>>2)+4*hi, lane^32 holds the other
// half). Row max/sum = 31 in-register ops + ONE shfl_xor(32) (vs 16 bpermutes
// + LDS P round-trip in the 16x16 version -- that chain was the 85-115us
// plateau, R3..R10). P packs via v_cvt_pk_bf16_f32 (16) + v_permlane32_swap
// (8, pure VALU): swap(W[rgA].w, W[rgB].w) yields BOTH halves of a PV B-frag.
// PV computes O^T = mfma(A=V[d][k], B=P^T[k][q]): O^T col=l&31=q, so the
// online-softmax alpha rescale is LANE-LOCAL (zero broadcasts).
// Shell = R10: balanced pairs (group 63-p then p -> 33 tiles per block),
// KV-split-3 over 3 waves, two LDS merges per block (stride 67, no conflicts).
// K pre-scaled by 1/sqrt(hs)*log2e in GEMM1 epilogue (log2-domain scores).
// q,k: [bh][t][64] bf16; v: [bh][64][t] bf16 (transposed); y: [4096][1024] bf16.
#define MOSTR 67
__global__ __launch_bounds__(192) void k_attn(const unsigned short* __restrict__ qb,
                                              const unsigned short* __restrict__ kb,
                                              const unsigned short* __restrict__ vb,
                                              unsigned short* __restrict__ yb) {
  __shared__ float Mo[3 * 32 * MOSTR];   // 25728 B partial O^T
  __shared__ float Lml[3][2][32];        // partial m, l per q
  // rid -> (xcd, bh, pair). 8 XCDs x 4 bh x 32 pairs = 1024 blocks.
  const int rid = blockIdx.x;
  const int xcd = rid & 7, i = rid >> 3;       // i in 0..127
  const int bh = xcd * 4 + (i & 3);
  const int p = i >> 2;                        // 0..31
  const int wave = threadIdx.x >> 6;           // 0..2
  const int lane = threadIdx.x & 63;
  const int l31 = lane & 31, hi = lane >> 5;
  const unsigned short* qh = qb + (size_t)bh * T_SEQ * HS;
  const unsigned short* kh = kb + (size_t)bh * T_SEQ * HS;
  const unsigned short* vh = vb + (size_t)bh * HS * T_SEQ;
  const int b = bh >> 4, h = bh & 15;

  for (int grp = 0; grp < 2; ++grp) {
    const int g = grp ? p : 63 - p;
    const int q0 = g * 32;
    const int nkt = (q0 >> 6) + 1;

    // Q B-frags: col=q=l31, k(d) = dd*16 + hi*8 + {0..7}
    bf16x8 qf[4];
#pragma unroll
    for (int dd = 0; dd < 4; ++dd)
      qf[dd] = *(const bf16x8*)&qh[(size_t)(q0 + l31) * HS + dd * 16 + hi * 8];

    f32x16 o2[2];                 // O^T acc: col=q=l31, rows d = db*32 + rowpat
#pragma unroll
    for (int db = 0; db < 2; ++db)
#pragma unroll
      for (int e = 0; e < 16; ++e) o2[db][e] = 0.f;
    float Mx = -INFINITY, Ls = 0.f;

    // prologue: K A-frags of this wave's first tile (rows <= 191 < T, safe)
    bf16x8 kf[2][4];
#pragma unroll
    for (int kbk = 0; kbk < 2; ++kbk)
#pragma unroll
      for (int dd = 0; dd < 4; ++dd)
        kf[kbk][dd] = *(const bf16x8*)&kh[(size_t)(wave * 64 + kbk * 32 + l31) * HS + dd * 16 + hi * 8];

    for (int kt = wave; kt < nkt; kt += 3) {
      const int kvb = kt * 64;

      // QK^T: s[kb] = S^T 32-key block (col=q=l31, row=key pattern)
      f32x16 s[2];
#pragma unroll
      for (int kbk = 0; kbk < 2; ++kbk) {
        f32x16 z;
#pragma unroll
        for (int e = 0; e < 16; ++e) z[e] = 0.f;
#pragma unroll
        for (int dd = 0; dd < 4; ++dd)
          z = __builtin_amdgcn_mfma_f32_32x32x16_bf16(kf[kbk][dd], qf[dd], z, 0, 0, 0);
        s[kbk] = z;
      }

      // prefetch K for this wave's next tile (kt+3); kf dead after QK MFMAs
      if (kt + 3 < nkt) {
        const int kvb2 = kvb + 192;
#pragma unroll
        for (int kbk = 0; kbk < 2; ++kbk)
#pragma unroll
          for (int dd = 0; dd < 4; ++dd)
            kf[kbk][dd] = *(const bf16x8*)&kh[(size_t)(kvb2 + kbk * 32 + l31) * HS + dd * 16 + hi * 8];
      }

      // V A-frags: row d = db*32 + l31, k(keys) = kvb + t16*16 + hi*8 + {0..7}
      bf16x8 vf[2][4];
#pragma unroll
      for (int db = 0; db < 2; ++db)
#pragma unroll
        for (int t16 = 0; t16 < 4; ++t16)
          vf[db][t16] = *(const bf16x8*)&vh[(size_t)(db * 32 + l31) * T_SEQ + kvb + t16 * 16 + hi * 8];

      // causal mask (only last tile of the group has kvb+63 > q0)
      if (kvb + 63 > q0) {
        const int qg = q0 + l31;
#pragma unroll
        for (int kbk = 0; kbk < 2; ++kbk)
#pragma unroll
          for (int r = 0; r < 16; ++r) {
            const int key = kvb + kbk * 32 + (r & 3) + 8 * (r >> 2) + 4 * hi;
            if (key > qg) s[kbk][r] = -3.0e38f;
          }
      }

      // row max: elementwise tree (31 fmax) + 1 cross-half shfl
      f32x16 tm;
#pragma unroll
      for (int e = 0; e < 16; ++e) tm[e] = fmaxf(s[0][e], s[1][e]);
      float m8[8];
#pragma unroll
      for (int e = 0; e < 8; ++e) m8[e] = fmaxf(tm[e], tm[e + 8]);
      float m4a = fmaxf(m8[0], m8[4]), m4b = fmaxf(m8[1], m8[5]);
      float m4c = fmaxf(m8[2], m8[6]), m4d = fmaxf(m8[3], m8[7]);
      float mx = fmaxf(fmaxf(m4a, m4b), fmaxf(m4c, m4d));
      mx = fmaxf(mx, __shfl_xor(mx, 32));
      const float newM = fmaxf(Mx, mx);
      const float alpha = __builtin_exp2f(Mx - newM);
      Mx = newM;

      // p = exp2(s - newM) in place; row sum (31 adds) + 1 cross-half shfl
#pragma unroll
      for (int kbk = 0; kbk < 2; ++kbk)
#pragma unroll
        for (int r = 0; r < 16; ++r) s[kbk][r] = __builtin_exp2f(s[kbk][r] - newM);
      f32x16 ts;
#pragma unroll
      for (int e = 0; e < 16; ++e) ts[e] = s[0][e] + s[1][e];
      float s8[8];
#pragma unroll
      for (int e = 0; e < 8; ++e) s8[e] = ts[e] + ts[e + 8];
      float rs = ((s8[0] + s8[1]) + (s8[2] + s8[3])) + ((s8[4] + s8[5]) + (s8[6] + s8[7]));
      rs += __shfl_xor(rs, 32);
      Ls = Ls * alpha + rs;

      // pack P: W[kb][rg] = 2 words (4 bf16, rows 8rg+4hi+{0..3})
      unsigned W0[2][4], W1[2][4];
#pragma unroll
      for (int kbk = 0; kbk < 2; ++kbk)
#pragma unroll
        for (int rg = 0; rg < 4; ++rg) {
          unsigned lo, hiw;
          asm("v_cvt_pk_bf16_f32 %0, %1, %2" : "=v"(lo) : "v"(s[kbk][4 * rg + 0]), "v"(s[kbk][4 * rg + 1]));
          asm("v_cvt_pk_bf16_f32 %0, %1, %2" : "=v"(hiw) : "v"(s[kbk][4 * rg + 2]), "v"(s[kbk][4 * rg + 3]));
          W0[kbk][rg] = lo; W1[kbk][rg] = hiw;
        }

      // build PV B-frags (P^T: col=q=l31, k = t16*16 + hi*8 + {0..7}) with
      // 8 permlane32_swap: swap(W[rgA].w, W[rgB].w) -> {frag.w, frag.w+2}
      // rgA = 2*(t16&1) (lo-half rows), rgB = rgA+1 (hi-half rows).
      bf16x8 pf[4];
#pragma unroll
      for (int t16 = 0; t16 < 4; ++t16) {
        const int kbk = t16 >> 1, par = t16 & 1;
        unsigned a0 = W0[kbk][2 * par], b0 = W0[kbk][2 * par + 1];
        unsigned a1 = W1[kbk][2 * par], b1 = W1[kbk][2 * par + 1];
        auto r0 = __builtin_amdgcn_permlane32_swap(a0, b0, false, false);
        auto r1 = __builtin_amdgcn_permlane32_swap(a1, b1, false, false);
        union { unsigned u[4]; bf16x8 v; } cv;
        cv.u[0] = (unsigned)r0[0]; cv.u[1] = (unsigned)r1[0];
        cv.u[2] = (unsigned)r0[1]; cv.u[3] = (unsigned)r1[1];
        pf[t16] = cv.v;
      }

      // lane-local O^T rescale (alpha is per-q = per-lane!)
#pragma unroll
      for (int db = 0; db < 2; ++db)
#pragma unroll
        for (int e = 0; e < 16; ++e) o2[db][e] *= alpha;

      // PV: O^T[d][q] += V[d][k] * P^T[k][q]
#pragma unroll
      for (int db = 0; db < 2; ++db)
#pragma unroll
        for (int t16 = 0; t16 < 4; ++t16)
          o2[db] = __builtin_amdgcn_mfma_f32_32x32x16_bf16(vf[db][t16], pf[t16], o2[db], 0, 0, 0);
    }

    // ---- publish partials ----
    if (hi == 0) {
      Lml[wave][0][l31] = Mx;
      Lml[wave][1][l31] = Ls;
    }
#pragma unroll
    for (int db = 0; db < 2; ++db)
#pragma unroll
      for (int r = 0; r < 16; ++r)
        Mo[wave * 32 * MOSTR + l31 * MOSTR + db * 32 + (r & 3) + 8 * (r >> 2) + 4 * hi] = o2[db][r];
    __syncthreads();

    // ---- distributed 3-way merge + store: 256 chunks of 8 cols ----
    for (int c = threadIdx.x; c < 256; c += 192) {
      const int rl = c >> 3, c0 = (c & 7) * 8;
      const float m0 = Lml[0][0][rl], m1 = Lml[1][0][rl], m2 = Lml[2][0][rl];
      const float l0 = Lml[0][1][rl], l1 = Lml[1][1][rl], l2 = Lml[2][1][rl];
      const float M = fmaxf(fmaxf(m0, m1), m2);
      const float a0 = __builtin_exp2f(m0 - M);
      const float a1 = __builtin_exp2f(m1 - M);
      const float a2 = __builtin_exp2f(m2 - M);
      const float inv = 1.0f / (a0 * l0 + a1 * l1 + a2 * l2);
      const float* O0 = &Mo[rl * MOSTR + c0];
      const float* O1 = O0 + 32 * MOSTR;
      const float* O2 = O0 + 64 * MOSTR;
      unsigned pk[4];
#pragma unroll
      for (int e = 0; e < 4; ++e) {
        float va = (a0 * O0[2 * e] + a1 * O1[2 * e] + a2 * O2[2 * e]) * inv;
        float vb2 = (a0 * O0[2 * e + 1] + a1 * O1[2 * e + 1] + a2 * O2[2 * e + 1]) * inv;
        pk[e] = (unsigned)f2bf(va) | ((unsigned)f2bf(vb2) << 16);
      }
      uint4 u; u.x = pk[0]; u.y = pk[1]; u.z = pk[2]; u.w = pk[3];
      *(uint4*)&yb[(size_t)(b * T_SEQ + q0 + rl) * CDIM + h * 64 + c0] = u;
    }
    __syncthreads();  // Mo reused by next group
  }
}

extern "C" void kernel_launch(void* const* d_in, const int* in_sizes, int n_in,
                              void* d_out, int out_size, void* d_ws, size_t ws_size,
                              hipStream_t stream) {
  (void)in_sizes; (void)n_in; (void)out_size; (void)ws_size;
  const float* x      = (const float*)d_in[0];
  const float* W_attn = (const float*)d_in[1];
  const float* b_attn = (const float*)d_in[2];
  const float* W_proj = (const float*)d_in[3];
  const float* b_proj = (const float*)d_in[4];
  float* out = (float*)d_out;
  char* ws = (char*)d_ws;

  unsigned short* xb  = (unsigned short*)(ws);              //  8 MiB [4096][1024]
  unsigned short* Wta = (unsigned short*)(ws + 8388608);    //  6 MiB [3072][1024]
  unsigned short* Wtp = (unsigned short*)(ws + 14680064);   //  2 MiB [1024][1024]
  unsigned short* qbf = (unsigned short*)(ws + 16777216);   //  8 MiB [32][2048][64]
  unsigned short* kbf = (unsigned short*)(ws + 25165824);   //  8 MiB [32][2048][64]
  unsigned short* vbf = (unsigned short*)(ws + 33554432);   //  8 MiB [32][64][2048]
  unsigned short* ybf = (unsigned short*)(ws + 41943040);   //  8 MiB [4096][1024]

  k_cvt_x<<<4096, 256, 0, stream>>>(x, xb);
  k_transpose<<<dim3(96, 32), 256, 0, stream>>>(W_attn, Wta, 1024, 3072);
  k_transpose<<<dim3(32, 32), 256, 0, stream>>>(W_proj, Wtp, 1024, 1024);
  k_gemm<0, 1024><<<dim3(32, 24), 256, 0, stream>>>(xb, Wta, b_attn, nullptr, qbf, kbf, vbf);
  k_attn<<<1024, 192, 0, stream>>>(qbf, kbf, vbf, ybf);
  k_gemm<1, 1024><<<dim3(32, 8), 256, 0, stream>>>(ybf, Wtp, b_proj, out, nullptr, nullptr, nullptr);
}

// Round 12
// 148.611 us; speedup vs baseline: 1.1720x; 1.0009x over previous
//
#include <hip/hip_runtime.h>
#include <stdint.h>

#define T_SEQ 2048
#define CDIM 1024
#define NHEAD 16
#define HS 64

typedef __bf16 bf16x8 __attribute__((ext_vector_type(8)));
typedef float f32x4 __attribute__((ext_vector_type(4)));
typedef float f32x16 __attribute__((ext_vector_type(16)));

__device__ __forceinline__ unsigned short f2bf(float f) {
  union { float f; unsigned u; } c; c.f = f;
  unsigned r = c.u + 0x7FFFu + ((c.u >> 16) & 1u);
  return (unsigned short)(r >> 16);
}

__device__ __forceinline__ void gload_lds16(const void* g, void* l) {
  __builtin_amdgcn_global_load_lds((__attribute__((address_space(1))) void*)(g),
                                   (__attribute__((address_space(3))) void*)(l),
                                   16, 0, 0);
}

// Cross-half (lane i <-> lane i^32) exchange via permlane32_swap (pure VALU,
// ~no latency vs ds_bpermute's ~120cy). Semantics verified by R11's passing
// pf construction: swap(a,b) = ([a.lo,b.lo], [a.hi,b.hi]).
__device__ __forceinline__ float xhalf_other(float x, int hi) {
  union { float f; unsigned u; } c; c.f = x;
  auto r = __builtin_amdgcn_permlane32_swap(c.u, c.u, false, false);
  union { unsigned u; float f; } lo_, hi_;
  lo_.u = (unsigned)r[0]; hi_.u = (unsigned)r[1];
  return hi ? lo_.f : hi_.f;
}

// x fp32 [4096][1024] -> bf16 same layout. 4 elems/thread.
__global__ __launch_bounds__(256) void k_cvt_x(const float* __restrict__ x,
                                               unsigned short* __restrict__ xb) {
  int i = blockIdx.x * 256 + threadIdx.x;
  float4 f = reinterpret_cast<const float4*>(x)[i];
  ushort4 u;
  u.x = f2bf(f.x); u.y = f2bf(f.y); u.z = f2bf(f.z); u.w = f2bf(f.w);
  reinterpret_cast<ushort4*>(xb)[i] = u;
}

// W [K][N] fp32 -> Wt [N][K] bf16 (tiled transpose)
__global__ __launch_bounds__(256) void k_transpose(const float* __restrict__ W,
                                                   unsigned short* __restrict__ Wt,
                                                   int K, int N) {
  __shared__ float tile[32][33];
  int n0 = blockIdx.x * 32, k0 = blockIdx.y * 32;
  int c = threadIdx.x & 31, r0 = threadIdx.x >> 5;
#pragma unroll
  for (int r = r0; r < 32; r += 8) tile[r][c] = W[(size_t)(k0 + r) * N + n0 + c];
  __syncthreads();
#pragma unroll
  for (int r = r0; r < 32; r += 8) Wt[(size_t)(n0 + r) * K + k0 + c] = f2bf(tile[c][r]);
}

// C = A[M][KD] * Bt[N][KD]^T + bias. 128x128 tile, 4 waves, BK=32.
// MODE 0: qkv scatter epilogue (bf16, K pre-scaled by 1/sqrt(hs)*log2e).
// MODE 1: fp32 out.
template <int MODE, int KD>
__global__ __launch_bounds__(256) void k_gemm(const unsigned short* __restrict__ A,
                                              const unsigned short* __restrict__ Bt,
                                              const float* __restrict__ bias,
                                              float* __restrict__ outF,
                                              unsigned short* __restrict__ qb,
                                              unsigned short* __restrict__ kb,
                                              unsigned short* __restrict__ vb) {
  __shared__ __align__(16) unsigned short Al[128 * 32];
  __shared__ __align__(16) unsigned short Bl[128 * 32];
  const int tid = threadIdx.x;
  const int wave = tid >> 6, lane = tid & 63;
  const int m0 = blockIdx.x * 128, n0 = blockIdx.y * 128;
  const int wr = (wave >> 1) * 64, wc = (wave & 1) * 64;
  const int srow = tid >> 2, scol = (tid & 3) * 8;
  const int ka = (lane >> 4) * 8;
  f32x4 acc[4][4];
#pragma unroll
  for (int m = 0; m < 4; ++m)
#pragma unroll
    for (int n = 0; n < 4; ++n) acc[m][n] = f32x4{0.f, 0.f, 0.f, 0.f};

  for (int k0 = 0; k0 < KD; k0 += 32) {
#pragma unroll
    for (int r = 0; r < 2; ++r) {
      gload_lds16(A + (size_t)(m0 + r * 64 + srow) * KD + k0 + scol,
                  (char*)Al + r * 4096 + wave * 1024);
      gload_lds16(Bt + (size_t)(n0 + r * 64 + srow) * KD + k0 + scol,
                  (char*)Bl + r * 4096 + wave * 1024);
    }
    __syncthreads();
    bf16x8 af[4], bfr[4];
#pragma unroll
    for (int m = 0; m < 4; ++m)
      af[m] = *(const bf16x8*)&Al[(wr + m * 16 + (lane & 15)) * 32 + ka];
#pragma unroll
    for (int n = 0; n < 4; ++n)
      bfr[n] = *(const bf16x8*)&Bl[(wc + n * 16 + (lane & 15)) * 32 + ka];
#pragma unroll
    for (int m = 0; m < 4; ++m)
#pragma unroll
      for (int n = 0; n < 4; ++n)
        acc[m][n] = __builtin_amdgcn_mfma_f32_16x16x32_bf16(af[m], bfr[n], acc[m][n], 0, 0, 0);
    __syncthreads();
  }

#pragma unroll
  for (int m = 0; m < 4; ++m)
#pragma unroll
    for (int n = 0; n < 4; ++n)
#pragma unroll
      for (int j = 0; j < 4; ++j) {
        int row = m0 + wr + m * 16 + (lane >> 4) * 4 + j;
        int col = n0 + wc + n * 16 + (lane & 15);
        float v = acc[m][n][j] + bias[col];
        if (MODE == 1) {
          outF[(size_t)row * CDIM + col] = v;
        } else {
          int which = col >> 10;
          int h = (col >> 6) & 15;
          int d = col & 63;
          int b = row >> 11, t = row & (T_SEQ - 1);
          int bh = b * NHEAD + h;
          // Fold attention scale (1/sqrt(64) * log2e) into K.
          unsigned short bv = f2bf(which == 1 ? v * 0.18033688f : v);
          if (which == 0)      qb[((size_t)bh * T_SEQ + t) * HS + d] = bv;
          else if (which == 1) kb[((size_t)bh * T_SEQ + t) * HS + d] = bv;
          else                 vb[((size_t)bh * HS + d) * T_SEQ + t] = bv;
        }
      }
}

// Flash attention: 32x32 lane-local softmax (R11) + SOFTWARE-PIPELINED QK +
// permlane cross-half reduces + defer-max (T13, THR=8).
// Pipeline: s_cur is loop-carried; QK(kt+3) issues at the END of iter kt
// (kf(kt+3) was loaded at iter-kt top), so its MFMA latency hides under the
// loop back-edge instead of heading the chain. Cross-half max/sum use
// permlane32_swap (VALU) instead of ds_bpermute shfls (~240cy/tile saved).
// Defer-max: if __all(mx <= Mx+8) keep old Mx -- skips alpha+32-mult rescale
// (P bounded by 2^8, fine in fp32 accum; merge renormalizes).
// Shell = R10/R11: balanced pairs (63-p then p -> 33 tiles/block), KV-split-3,
// two LDS merges per block (stride 67, conflict-free).
// K pre-scaled by 1/sqrt(hs)*log2e in GEMM1 epilogue (log2-domain scores).
// q,k: [bh][t][64] bf16; v: [bh][64][t] bf16 (transposed); y: [4096][1024] bf16.
#define MOSTR 67
__global__ __launch_bounds__(192) void k_attn(const unsigned short* __restrict__ qb,
                                              const unsigned short* __restrict__ kb,
                                              const unsigned short* __restrict__ vb,
                                              unsigned short* __restrict__ yb) {
  __shared__ float Mo[3 * 32 * MOSTR];   // 25728 B partial O^T
  __shared__ float Lml[3][2][32];        // partial m, l per q
  // rid -> (xcd, bh, pair). 8 XCDs x 4 bh x 32 pairs = 1024 blocks.
  const int rid = blockIdx.x;
  const int xcd = rid & 7, i = rid >> 3;       // i in 0..127
  const int bh = xcd * 4 + (i & 3);
  const int p = i >> 2;                        // 0..31
  const int wave = threadIdx.x >> 6;           // 0..2
  const int lane = threadIdx.x & 63;
  const int l31 = lane & 31, hi = lane >> 5;
  const unsigned short* qh = qb + (size_t)bh * T_SEQ * HS;
  const unsigned short* kh = kb + (size_t)bh * T_SEQ * HS;
  const unsigned short* vh = vb + (size_t)bh * HS * T_SEQ;
  const int b = bh >> 4, h = bh & 15;

  for (int grp = 0; grp < 2; ++grp) {
    const int g = grp ? p : 63 - p;
    const int q0 = g * 32;
    const int nkt = (q0 >> 6) + 1;

    // Q B-frags: col=q=l31, k(d) = dd*16 + hi*8 + {0..7}
    bf16x8 qf[4];
#pragma unroll
    for (int dd = 0; dd < 4; ++dd)
      qf[dd] = *(const bf16x8*)&qh[(size_t)(q0 + l31) * HS + dd * 16 + hi * 8];

    f32x16 o2[2];                 // O^T acc: col=q=l31, rows d = db*32 + rowpat
#pragma unroll
    for (int db = 0; db < 2; ++db)
#pragma unroll
      for (int e = 0; e < 16; ++e) o2[db][e] = 0.f;
    float Mx = -INFINITY, Ls = 0.f;

    // prologue: K A-frags + QK of this wave's first tile (rows <= 191, safe)
    bf16x8 kf[2][4];
#pragma unroll
    for (int kbk = 0; kbk < 2; ++kbk)
#pragma unroll
      for (int dd = 0; dd < 4; ++dd)
        kf[kbk][dd] = *(const bf16x8*)&kh[(size_t)(wave * 64 + kbk * 32 + l31) * HS + dd * 16 + hi * 8];
    f32x16 s[2];
#pragma unroll
    for (int kbk = 0; kbk < 2; ++kbk) {
      f32x16 z;
#pragma unroll
      for (int e = 0; e < 16; ++e) z[e] = 0.f;
#pragma unroll
      for (int dd = 0; dd < 4; ++dd)
        z = __builtin_amdgcn_mfma_f32_32x32x16_bf16(kf[kbk][dd], qf[dd], z, 0, 0, 0);
      s[kbk] = z;
    }

    for (int kt = wave; kt < nkt; kt += 3) {
      const int kvb = kt * 64;
      const bool more = (kt + 3 < nkt);

      // issue K loads for tile kt+3 (kf regs free: QK(kt) already computed)
      if (more) {
        const int kvb2 = kvb + 192;
#pragma unroll
        for (int kbk = 0; kbk < 2; ++kbk)
#pragma unroll
          for (int dd = 0; dd < 4; ++dd)
            kf[kbk][dd] = *(const bf16x8*)&kh[(size_t)(kvb2 + kbk * 32 + l31) * HS + dd * 16 + hi * 8];
      }
      // issue V loads for THIS tile (consumed after softmax -> latency hidden)
      bf16x8 vf[2][4];
#pragma unroll
      for (int db = 0; db < 2; ++db)
#pragma unroll
        for (int t16 = 0; t16 < 4; ++t16)
          vf[db][t16] = *(const bf16x8*)&vh[(size_t)(db * 32 + l31) * T_SEQ + kvb + t16 * 16 + hi * 8];

      // causal mask (only the group's last tile has kvb+63 > q0)
      if (kvb + 63 > q0) {
        const int qg = q0 + l31;
#pragma unroll
        for (int kbk = 0; kbk < 2; ++kbk)
#pragma unroll
          for (int r = 0; r < 16; ++r) {
            const int key = kvb + kbk * 32 + (r & 3) + 8 * (r >> 2) + 4 * hi;
            if (key > qg) s[kbk][r] = -3.0e38f;
          }
      }

      // row max: in-register tree (31 fmax) + permlane cross-half
      f32x16 tm;
#pragma unroll
      for (int e = 0; e < 16; ++e) tm[e] = fmaxf(s[0][e], s[1][e]);
      float m8[8];
#pragma unroll
      for (int e = 0; e < 8; ++e) m8[e] = fmaxf(tm[e], tm[e + 8]);
      float m4a = fmaxf(m8[0], m8[4]), m4b = fmaxf(m8[1], m8[5]);
      float m4c = fmaxf(m8[2], m8[6]), m4d = fmaxf(m8[3], m8[7]);
      float mx = fmaxf(fmaxf(m4a, m4b), fmaxf(m4c, m4d));
      mx = fmaxf(mx, xhalf_other(mx, hi));

      // defer-max (T13): skip rescale while max growth <= 8 (P <= 2^8).
      if (!__all(mx <= Mx + 8.f)) {
        const float newM = fmaxf(Mx, mx);
        const float alpha = __builtin_exp2f(Mx - newM);
        Mx = newM;
        Ls *= alpha;
#pragma unroll
        for (int db = 0; db < 2; ++db)
#pragma unroll
          for (int e = 0; e < 16; ++e) o2[db][e] *= alpha;
      }

      // p = exp2(s - Mx) in place; row sum (31 adds) + permlane cross-half
#pragma unroll
      for (int kbk = 0; kbk < 2; ++kbk)
#pragma unroll
        for (int r = 0; r < 16; ++r) s[kbk][r] = __builtin_exp2f(s[kbk][r] - Mx);
      f32x16 ts;
#pragma unroll
      for (int e = 0; e < 16; ++e) ts[e] = s[0][e] + s[1][e];
      float s8[8];
#pragma unroll
      for (int e = 0; e < 8; ++e) s8[e] = ts[e] + ts[e + 8];
      float rs = ((s8[0] + s8[1]) + (s8[2] + s8[3])) + ((s8[4] + s8[5]) + (s8[6] + s8[7]));
      rs += xhalf_other(rs, hi);
      Ls += rs;

      // pack P: W[kb][rg] = 2 words (4 bf16, rows 8rg+4hi+{0..3})
      unsigned W0[2][4], W1[2][4];
#pragma unroll
      for (int kbk = 0; kbk < 2; ++kbk)
#pragma unroll
        for (int rg = 0; rg < 4; ++rg) {
          unsigned lo, hiw;
          asm("v_cvt_pk_bf16_f32 %0, %1, %2" : "=v"(lo) : "v"(s[kbk][4 * rg + 0]), "v"(s[kbk][4 * rg + 1]));
          asm("v_cvt_pk_bf16_f32 %0, %1, %2" : "=v"(hiw) : "v"(s[kbk][4 * rg + 2]), "v"(s[kbk][4 * rg + 3]));
          W0[kbk][rg] = lo; W1[kbk][rg] = hiw;
        }

      // build PV B-frags (P^T: col=q=l31, k = t16*16 + hi*8 + {0..7}) with
      // 8 permlane32_swap: swap(W[rgA].w, W[rgB].w) -> both frag halves.
      bf16x8 pf[4];
#pragma unroll
      for (int t16 = 0; t16 < 4; ++t16) {
        const int kbk = t16 >> 1, par = t16 & 1;
        unsigned a0 = W0[kbk][2 * par], b0 = W0[kbk][2 * par + 1];
        unsigned a1 = W1[kbk][2 * par], b1 = W1[kbk][2 * par + 1];
        auto r0 = __builtin_amdgcn_permlane32_swap(a0, b0, false, false);
        auto r1 = __builtin_amdgcn_permlane32_swap(a1, b1, false, false);
        union { unsigned u[4]; bf16x8 v; } cv;
        cv.u[0] = (unsigned)r0[0]; cv.u[1] = (unsigned)r1[0];
        cv.u[2] = (unsigned)r0[1]; cv.u[3] = (unsigned)r1[1];
        pf[t16] = cv.v;
      }

      // PV: O^T[d][q] += V[d][k] * P^T[k][q]
#pragma unroll
      for (int db = 0; db < 2; ++db)
#pragma unroll
        for (int t16 = 0; t16 < 4; ++t16)
          o2[db] = __builtin_amdgcn_mfma_f32_32x32x16_bf16(vf[db][t16], pf[t16], o2[db], 0, 0, 0);

      // QK for tile kt+3 at iteration END: kf loads (issued this iter) had the
      // whole softmax+PV to land; MFMA latency hides under the loop back-edge.
      if (more) {
#pragma unroll
        for (int kbk = 0; kbk < 2; ++kbk) {
          f32x16 z;
#pragma unroll
          for (int e = 0; e < 16; ++e) z[e] = 0.f;
#pragma unroll
          for (int dd = 0; dd < 4; ++dd)
            z = __builtin_amdgcn_mfma_f32_32x32x16_bf16(kf[kbk][dd], qf[dd], z, 0, 0, 0);
          s[kbk] = z;
        }
      }
    }

    // ---- publish partials ----
    if (hi == 0) {
      Lml[wave][0][l31] = Mx;
      Lml[wave][1][l31] = Ls;
    }
#pragma unroll
    for (int db = 0; db < 2; ++db)
#pragma unroll
      for (int r = 0; r < 16; ++r)
        Mo[wave * 32 * MOSTR + l31 * MOSTR + db * 32 + (r & 3) + 8 * (r >> 2) + 4 * hi] = o2[db][r];
    __syncthreads();

    // ---- distributed 3-way merge + store: 256 chunks of 8 cols ----
    for (int c = threadIdx.x; c < 256; c += 192) {
      const int rl = c >> 3, c0 = (c & 7) * 8;
      const float m0 = Lml[0][0][rl], m1 = Lml[1][0][rl], m2 = Lml[2][0][rl];
      const float l0 = Lml[0][1][rl], l1 = Lml[1][1][rl], l2 = Lml[2][1][rl];
      const float M = fmaxf(fmaxf(m0, m1), m2);
      const float a0 = __builtin_exp2f(m0 - M);
      const float a1 = __builtin_exp2f(m1 - M);
      const float a2 = __builtin_exp2f(m2 - M);
      const float inv = 1.0f / (a0 * l0 + a1 * l1 + a2 * l2);
      const float* O0 = &Mo[rl * MOSTR + c0];
      const float* O1 = O0 + 32 * MOSTR;
      const float* O2 = O0 + 64 * MOSTR;
      unsigned pk[4];
#pragma unroll
      for (int e = 0; e < 4; ++e) {
        float va = (a0 * O0[2 * e] + a1 * O1[2 * e] + a2 * O2[2 * e]) * inv;
        float vb2 = (a0 * O0[2 * e + 1] + a1 * O1[2 * e + 1] + a2 * O2[2 * e + 1]) * inv;
        pk[e] = (unsigned)f2bf(va) | ((unsigned)f2bf(vb2) << 16);
      }
      uint4 u; u.x = pk[0]; u.y = pk[1]; u.z = pk[2]; u.w = pk[3];
      *(uint4*)&yb[(size_t)(b * T_SEQ + q0 + rl) * CDIM + h * 64 + c0] = u;
    }
    __syncthreads();  // Mo reused by next group
  }
}

extern "C" void kernel_launch(void* const* d_in, const int* in_sizes, int n_in,
                              void* d_out, int out_size, void* d_ws, size_t ws_size,
                              hipStream_t stream) {
  (void)in_sizes; (void)n_in; (void)out_size; (void)ws_size;
  const float* x      = (const float*)d_in[0];
  const float* W_attn = (const float*)d_in[1];
  const float* b_attn = (const float*)d_in[2];
  const float* W_proj = (const float*)d_in[3];
  const float* b_proj = (const float*)d_in[4];
  float* out = (float*)d_out;
  char* ws = (char*)d_ws;

  unsigned short* xb  = (unsigned short*)(ws);              //  8 MiB [4096][1024]
  unsigned short* Wta = (unsigned short*)(ws + 8388608);    //  6 MiB [3072][1024]
  unsigned short* Wtp = (unsigned short*)(ws + 14680064);   //  2 MiB [1024][1024]
  unsigned short* qbf = (unsigned short*)(ws + 16777216);   //  8 MiB [32][2048][64]
  unsigned short* kbf = (unsigned short*)(ws + 25165824);   //  8 MiB [32][2048][64]
  unsigned short* vbf = (unsigned short*)(ws + 33554432);   //  8 MiB [32][64][2048]
  unsigned short* ybf = (unsigned short*)(ws + 41943040);   //  8 MiB [4096][1024]

  k_cvt_x<<<4096, 256, 0, stream>>>(x, xb);
  k_transpose<<<dim3(96, 32), 256, 0, stream>>>(W_attn, Wta, 1024, 3072);
  k_transpose<<<dim3(32, 32), 256, 0, stream>>>(W_proj, Wtp, 1024, 1024);
  k_gemm<0, 1024><<<dim3(32, 24), 256, 0, stream>>>(xb, Wta, b_attn, nullptr, qbf, kbf, vbf);
  k_attn<<<1024, 192, 0, stream>>>(qbf, kbf, vbf, ybf);
  k_gemm<1, 1024><<<dim3(32, 8), 256, 0, stream>>>(ybf, Wtp, b_proj, out, nullptr, nullptr, nullptr);
}

// Round 13
// 130.538 us; speedup vs baseline: 1.3343x; 1.1385x over previous
//
#include <hip/hip_runtime.h>
#include <stdint.h>

#define T_SEQ 2048
#define CDIM 1024
#define NHEAD 16
#define HS 64

typedef __bf16 bf16x8 __attribute__((ext_vector_type(8)));
typedef float f32x4 __attribute__((ext_vector_type(4)));
typedef float f32x16 __attribute__((ext_vector_type(16)));

__device__ __forceinline__ unsigned short f2bf(float f) {
  union { float f; unsigned u; } c; c.f = f;
  unsigned r = c.u + 0x7FFFu + ((c.u >> 16) & 1u);
  return (unsigned short)(r >> 16);
}

__device__ __forceinline__ void gload_lds16(const void* g, void* l) {
  __builtin_amdgcn_global_load_lds((__attribute__((address_space(1))) void*)(g),
                                   (__attribute__((address_space(3))) void*)(l),
                                   16, 0, 0);
}

// Cross-half (lane i <-> lane i^32) exchange via permlane32_swap (pure VALU).
__device__ __forceinline__ float xhalf_other(float x, int hi) {
  union { float f; unsigned u; } c; c.f = x;
  auto r = __builtin_amdgcn_permlane32_swap(c.u, c.u, false, false);
  union { unsigned u; float f; } lo_, hi_;
  lo_.u = (unsigned)r[0]; hi_.u = (unsigned)r[1];
  return hi ? lo_.f : hi_.f;
}

// x fp32 [4096][1024] -> bf16 same layout. 4 elems/thread.
__global__ __launch_bounds__(256) void k_cvt_x(const float* __restrict__ x,
                                               unsigned short* __restrict__ xb) {
  int i = blockIdx.x * 256 + threadIdx.x;
  float4 f = reinterpret_cast<const float4*>(x)[i];
  ushort4 u;
  u.x = f2bf(f.x); u.y = f2bf(f.y); u.z = f2bf(f.z); u.w = f2bf(f.w);
  reinterpret_cast<ushort4*>(xb)[i] = u;
}

// W [K][N] fp32 -> Wt [N][K] bf16 (tiled transpose)
__global__ __launch_bounds__(256) void k_transpose(const float* __restrict__ W,
                                                   unsigned short* __restrict__ Wt,
                                                   int K, int N) {
  __shared__ float tile[32][33];
  int n0 = blockIdx.x * 32, k0 = blockIdx.y * 32;
  int c = threadIdx.x & 31, r0 = threadIdx.x >> 5;
#pragma unroll
  for (int r = r0; r < 32; r += 8) tile[r][c] = W[(size_t)(k0 + r) * N + n0 + c];
  __syncthreads();
#pragma unroll
  for (int r = r0; r < 32; r += 8) Wt[(size_t)(n0 + r) * K + k0 + c] = f2bf(tile[c][r]);
}

// C = A[M][KD] * Bt[N][KD]^T + bias. 128x128 tile, 4 waves, BK=32.
// MODE 0: qkv scatter epilogue in FRAGMENT-LINEAR layout (see k_attn header).
//   R12 diagnosis: attn fragment loads from row-major q/k/v fragmented into
//   ~32 transactions each (32 rows x 32B, 128B apart) -> ~512 VMEM
//   transactions per wave-tile -> attn was VMEM-transaction-bound (~50us
//   stall). Storing Q/K/V in the exact per-lane consumption order makes every
//   attn fragment load one dense 1KB block (~16x fewer transactions).
//   Per 64-token tile (4096 elems): K/Q slot = kbk*2048 + dd*512 + l31*16
//   + hi*8 + j  (row r = kbk*32+l31, d = dd*16+hi*8+j);
//   V slot = db*2048 + t16*512 + l31*16 + hi*8 + j (d = db*32+l31,
//   key kk = t16*16+hi*8+j). K pre-scaled by 1/sqrt(hs)*log2e.
// MODE 1: fp32 out.
template <int MODE, int KD>
__global__ __launch_bounds__(256) void k_gemm(const unsigned short* __restrict__ A,
                                              const unsigned short* __restrict__ Bt,
                                              const float* __restrict__ bias,
                                              float* __restrict__ outF,
                                              unsigned short* __restrict__ qb,
                                              unsigned short* __restrict__ kb,
                                              unsigned short* __restrict__ vb) {
  __shared__ __align__(16) unsigned short Al[128 * 32];
  __shared__ __align__(16) unsigned short Bl[128 * 32];
  const int tid = threadIdx.x;
  const int wave = tid >> 6, lane = tid & 63;
  const int m0 = blockIdx.x * 128, n0 = blockIdx.y * 128;
  const int wr = (wave >> 1) * 64, wc = (wave & 1) * 64;
  const int srow = tid >> 2, scol = (tid & 3) * 8;
  const int ka = (lane >> 4) * 8;
  f32x4 acc[4][4];
#pragma unroll
  for (int m = 0; m < 4; ++m)
#pragma unroll
    for (int n = 0; n < 4; ++n) acc[m][n] = f32x4{0.f, 0.f, 0.f, 0.f};

  for (int k0 = 0; k0 < KD; k0 += 32) {
#pragma unroll
    for (int r = 0; r < 2; ++r) {
      gload_lds16(A + (size_t)(m0 + r * 64 + srow) * KD + k0 + scol,
                  (char*)Al + r * 4096 + wave * 1024);
      gload_lds16(Bt + (size_t)(n0 + r * 64 + srow) * KD + k0 + scol,
                  (char*)Bl + r * 4096 + wave * 1024);
    }
    __syncthreads();
    bf16x8 af[4], bfr[4];
#pragma unroll
    for (int m = 0; m < 4; ++m)
      af[m] = *(const bf16x8*)&Al[(wr + m * 16 + (lane & 15)) * 32 + ka];
#pragma unroll
    for (int n = 0; n < 4; ++n)
      bfr[n] = *(const bf16x8*)&Bl[(wc + n * 16 + (lane & 15)) * 32 + ka];
#pragma unroll
    for (int m = 0; m < 4; ++m)
#pragma unroll
      for (int n = 0; n < 4; ++n)
        acc[m][n] = __builtin_amdgcn_mfma_f32_16x16x32_bf16(af[m], bfr[n], acc[m][n], 0, 0, 0);
    __syncthreads();
  }

#pragma unroll
  for (int m = 0; m < 4; ++m)
#pragma unroll
    for (int n = 0; n < 4; ++n)
#pragma unroll
      for (int j = 0; j < 4; ++j) {
        int row = m0 + wr + m * 16 + (lane >> 4) * 4 + j;
        int col = n0 + wc + n * 16 + (lane & 15);
        float v = acc[m][n][j] + bias[col];
        if (MODE == 1) {
          outF[(size_t)row * CDIM + col] = v;
        } else {
          int which = col >> 10;
          int h = (col >> 6) & 15;
          int d = col & 63;
          int b = row >> 11, t = row & (T_SEQ - 1);
          int bh = b * NHEAD + h;
          // Fold attention scale (1/sqrt(64) * log2e) into K.
          unsigned short bv = f2bf(which == 1 ? v * 0.18033688f : v);
          size_t tb = ((size_t)bh * 32 + (t >> 6)) * 4096;
          if (which == 2) {
            vb[tb + (d >> 5) * 2048 + ((t >> 4) & 3) * 512 + (d & 31) * 16 +
               ((t >> 3) & 1) * 8 + (t & 7)] = bv;
          } else {
            size_t a = tb + ((t >> 5) & 1) * 2048 + (d >> 4) * 512 + (t & 31) * 16 +
                       ((d >> 3) & 1) * 8 + (d & 7);
            if (which == 0) qb[a] = bv; else kb[a] = bv;
          }
        }
      }
}

// Flash attention: 32x32 lane-local softmax + pipelined QK + permlane reduces
// + defer-max (R12) with FRAGMENT-LINEAR Q/K/V (this round's change).
// Every fragment load is now one dense 1KB wave access (lane-contiguous 16B),
// ~16x fewer VMEM transactions than the row-major layout -- R12's bound.
// Shell: balanced pairs (63-p then p -> 33 tiles/block), KV-split-3 over
// 3 waves, two LDS merges per block (stride 67, conflict-free).
// q,k,v fragment-linear per 64-token tile (see k_gemm header); y row-major.
#define MOSTR 67
__global__ __launch_bounds__(192) void k_attn(const unsigned short* __restrict__ qb,
                                              const unsigned short* __restrict__ kb,
                                              const unsigned short* __restrict__ vb,
                                              unsigned short* __restrict__ yb) {
  __shared__ float Mo[3 * 32 * MOSTR];   // 25728 B partial O^T
  __shared__ float Lml[3][2][32];        // partial m, l per q
  // rid -> (xcd, bh, pair). 8 XCDs x 4 bh x 32 pairs = 1024 blocks.
  const int rid = blockIdx.x;
  const int xcd = rid & 7, i = rid >> 3;       // i in 0..127
  const int bh = xcd * 4 + (i & 3);
  const int p = i >> 2;                        // 0..31
  const int wave = threadIdx.x >> 6;           // 0..2
  const int lane = threadIdx.x & 63;
  const int l31 = lane & 31, hi = lane >> 5;
  const unsigned short* qh = qb + (size_t)bh * T_SEQ * HS;
  const unsigned short* kh = kb + (size_t)bh * T_SEQ * HS;
  const unsigned short* vh = vb + (size_t)bh * T_SEQ * HS;
  const int b = bh >> 4, h = bh & 15;
  const int lbase = l31 * 16 + hi * 8;         // per-lane offset within a 512-slab

  for (int grp = 0; grp < 2; ++grp) {
    const int g = grp ? p : 63 - p;
    const int q0 = g * 32;
    const int nkt = (q0 >> 6) + 1;

    // Q B-frags (fragment-linear): col=q=l31, k(d) = dd*16 + hi*8 + {0..7}
    const size_t qbase = (size_t)(g >> 1) * 4096 + (size_t)(g & 1) * 2048;
    bf16x8 qf[4];
#pragma unroll
    for (int dd = 0; dd < 4; ++dd)
      qf[dd] = *(const bf16x8*)&qh[qbase + dd * 512 + lbase];

    f32x16 o2[2];                 // O^T acc: col=q=l31, rows d = db*32 + rowpat
#pragma unroll
    for (int db = 0; db < 2; ++db)
#pragma unroll
      for (int e = 0; e < 16; ++e) o2[db][e] = 0.f;
    float Mx = -INFINITY, Ls = 0.f;

    // prologue: K A-frags + QK of this wave's first tile
    bf16x8 kf[2][4];
#pragma unroll
    for (int kbk = 0; kbk < 2; ++kbk)
#pragma unroll
      for (int dd = 0; dd < 4; ++dd)
        kf[kbk][dd] = *(const bf16x8*)&kh[(size_t)wave * 4096 + kbk * 2048 + dd * 512 + lbase];
    f32x16 s[2];
#pragma unroll
    for (int kbk = 0; kbk < 2; ++kbk) {
      f32x16 z;
#pragma unroll
      for (int e = 0; e < 16; ++e) z[e] = 0.f;
#pragma unroll
      for (int dd = 0; dd < 4; ++dd)
        z = __builtin_amdgcn_mfma_f32_32x32x16_bf16(kf[kbk][dd], qf[dd], z, 0, 0, 0);
      s[kbk] = z;
    }

    for (int kt = wave; kt < nkt; kt += 3) {
      const int kvb = kt * 64;
      const bool more = (kt + 3 < nkt);

      // issue K loads for tile kt+3 (kf regs free: QK(kt) already computed)
      if (more) {
#pragma unroll
        for (int kbk = 0; kbk < 2; ++kbk)
#pragma unroll
          for (int dd = 0; dd < 4; ++dd)
            kf[kbk][dd] = *(const bf16x8*)&kh[(size_t)(kt + 3) * 4096 + kbk * 2048 + dd * 512 + lbase];
      }
      // issue V loads for THIS tile (consumed after softmax -> latency hidden)
      bf16x8 vf[2][4];
#pragma unroll
      for (int db = 0; db < 2; ++db)
#pragma unroll
        for (int t16 = 0; t16 < 4; ++t16)
          vf[db][t16] = *(const bf16x8*)&vh[(size_t)kt * 4096 + db * 2048 + t16 * 512 + lbase];

      // causal mask (only the group's last tile has kvb+63 > q0)
      if (kvb + 63 > q0) {
        const int qg = q0 + l31;
#pragma unroll
        for (int kbk = 0; kbk < 2; ++kbk)
#pragma unroll
          for (int r = 0; r < 16; ++r) {
            const int key = kvb + kbk * 32 + (r & 3) + 8 * (r >> 2) + 4 * hi;
            if (key > qg) s[kbk][r] = -3.0e38f;
          }
      }

      // row max: in-register tree (31 fmax) + permlane cross-half
      f32x16 tm;
#pragma unroll
      for (int e = 0; e < 16; ++e) tm[e] = fmaxf(s[0][e], s[1][e]);
      float m8[8];
#pragma unroll
      for (int e = 0; e < 8; ++e) m8[e] = fmaxf(tm[e], tm[e + 8]);
      float m4a = fmaxf(m8[0], m8[4]), m4b = fmaxf(m8[1], m8[5]);
      float m4c = fmaxf(m8[2], m8[6]), m4d = fmaxf(m8[3], m8[7]);
      float mx = fmaxf(fmaxf(m4a, m4b), fmaxf(m4c, m4d));
      mx = fmaxf(mx, xhalf_other(mx, hi));

      // defer-max (T13): skip rescale while max growth <= 8 (P <= 2^8).
      if (!__all(mx <= Mx + 8.f)) {
        const float newM = fmaxf(Mx, mx);
        const float alpha = __builtin_exp2f(Mx - newM);
        Mx = newM;
        Ls *= alpha;
#pragma unroll
        for (int db = 0; db < 2; ++db)
#pragma unroll
          for (int e = 0; e < 16; ++e) o2[db][e] *= alpha;
      }

      // p = exp2(s - Mx) in place; row sum (31 adds) + permlane cross-half
#pragma unroll
      for (int kbk = 0; kbk < 2; ++kbk)
#pragma unroll
        for (int r = 0; r < 16; ++r) s[kbk][r] = __builtin_exp2f(s[kbk][r] - Mx);
      f32x16 ts;
#pragma unroll
      for (int e = 0; e < 16; ++e) ts[e] = s[0][e] + s[1][e];
      float s8[8];
#pragma unroll
      for (int e = 0; e < 8; ++e) s8[e] = ts[e] + ts[e + 8];
      float rs = ((s8[0] + s8[1]) + (s8[2] + s8[3])) + ((s8[4] + s8[5]) + (s8[6] + s8[7]));
      rs += xhalf_other(rs, hi);
      Ls += rs;

      // pack P: W[kb][rg] = 2 words (4 bf16, rows 8rg+4hi+{0..3})
      unsigned W0[2][4], W1[2][4];
#pragma unroll
      for (int kbk = 0; kbk < 2; ++kbk)
#pragma unroll
        for (int rg = 0; rg < 4; ++rg) {
          unsigned lo, hiw;
          asm("v_cvt_pk_bf16_f32 %0, %1, %2" : "=v"(lo) : "v"(s[kbk][4 * rg + 0]), "v"(s[kbk][4 * rg + 1]));
          asm("v_cvt_pk_bf16_f32 %0, %1, %2" : "=v"(hiw) : "v"(s[kbk][4 * rg + 2]), "v"(s[kbk][4 * rg + 3]));
          W0[kbk][rg] = lo; W1[kbk][rg] = hiw;
        }

      // build PV B-frags (P^T: col=q=l31, k = t16*16 + hi*8 + {0..7}) with
      // 8 permlane32_swap: swap(W[rgA].w, W[rgB].w) -> both frag halves.
      bf16x8 pf[4];
#pragma unroll
      for (int t16 = 0; t16 < 4; ++t16) {
        const int kbk = t16 >> 1, par = t16 & 1;
        unsigned a0 = W0[kbk][2 * par], b0 = W0[kbk][2 * par + 1];
        unsigned a1 = W1[kbk][2 * par], b1 = W1[kbk][2 * par + 1];
        auto r0 = __builtin_amdgcn_permlane32_swap(a0, b0, false, false);
        auto r1 = __builtin_amdgcn_permlane32_swap(a1, b1, false, false);
        union { unsigned u[4]; bf16x8 v; } cv;
        cv.u[0] = (unsigned)r0[0]; cv.u[1] = (unsigned)r1[0];
        cv.u[2] = (unsigned)r0[1]; cv.u[3] = (unsigned)r1[1];
        pf[t16] = cv.v;
      }

      // PV: O^T[d][q] += V[d][k] * P^T[k][q]
#pragma unroll
      for (int db = 0; db < 2; ++db)
#pragma unroll
        for (int t16 = 0; t16 < 4; ++t16)
          o2[db] = __builtin_amdgcn_mfma_f32_32x32x16_bf16(vf[db][t16], pf[t16], o2[db], 0, 0, 0);

      // QK for tile kt+3 at iteration END: kf loads (issued this iter) had the
      // whole softmax+PV to land; MFMA latency hides under the loop back-edge.
      if (more) {
#pragma unroll
        for (int kbk = 0; kbk < 2; ++kbk) {
          f32x16 z;
#pragma unroll
          for (int e = 0; e < 16; ++e) z[e] = 0.f;
#pragma unroll
          for (int dd = 0; dd < 4; ++dd)
            z = __builtin_amdgcn_mfma_f32_32x32x16_bf16(kf[kbk][dd], qf[dd], z, 0, 0, 0);
          s[kbk] = z;
        }
      }
    }

    // ---- publish partials ----
    if (hi == 0) {
      Lml[wave][0][l31] = Mx;
      Lml[wave][1][l31] = Ls;
    }
#pragma unroll
    for (int db = 0; db < 2; ++db)
#pragma unroll
      for (int r = 0; r < 16; ++r)
        Mo[wave * 32 * MOSTR + l31 * MOSTR + db * 32 + (r & 3) + 8 * (r >> 2) + 4 * hi] = o2[db][r];
    __syncthreads();

    // ---- distributed 3-way merge + store: 256 chunks of 8 cols ----
    for (int c = threadIdx.x; c < 256; c += 192) {
      const int rl = c >> 3, c0 = (c & 7) * 8;
      const float m0 = Lml[0][0][rl], m1 = Lml[1][0][rl], m2 = Lml[2][0][rl];
      const float l0 = Lml[0][1][rl], l1 = Lml[1][1][rl], l2 = Lml[2][1][rl];
      const float M = fmaxf(fmaxf(m0, m1), m2);
      const float a0 = __builtin_exp2f(m0 - M);
      const float a1 = __builtin_exp2f(m1 - M);
      const float a2 = __builtin_exp2f(m2 - M);
      const float inv = 1.0f / (a0 * l0 + a1 * l1 + a2 * l2);
      const float* O0 = &Mo[rl * MOSTR + c0];
      const float* O1 = O0 + 32 * MOSTR;
      const float* O2 = O0 + 64 * MOSTR;
      unsigned pk[4];
#pragma unroll
      for (int e = 0; e < 4; ++e) {
        float va = (a0 * O0[2 * e] + a1 * O1[2 * e] + a2 * O2[2 * e]) * inv;
        float vb2 = (a0 * O0[2 * e + 1] + a1 * O1[2 * e + 1] + a2 * O2[2 * e + 1]) * inv;
        pk[e] = (unsigned)f2bf(va) | ((unsigned)f2bf(vb2) << 16);
      }
      uint4 u; u.x = pk[0]; u.y = pk[1]; u.z = pk[2]; u.w = pk[3];
      *(uint4*)&yb[(size_t)(b * T_SEQ + q0 + rl) * CDIM + h * 64 + c0] = u;
    }
    __syncthreads();  // Mo reused by next group
  }
}

extern "C" void kernel_launch(void* const* d_in, const int* in_sizes, int n_in,
                              void* d_out, int out_size, void* d_ws, size_t ws_size,
                              hipStream_t stream) {
  (void)in_sizes; (void)n_in; (void)out_size; (void)ws_size;
  const float* x      = (const float*)d_in[0];
  const float* W_attn = (const float*)d_in[1];
  const float* b_attn = (const float*)d_in[2];
  const float* W_proj = (const float*)d_in[3];
  const float* b_proj = (const float*)d_in[4];
  float* out = (float*)d_out;
  char* ws = (char*)d_ws;

  unsigned short* xb  = (unsigned short*)(ws);              //  8 MiB [4096][1024]
  unsigned short* Wta = (unsigned short*)(ws + 8388608);    //  6 MiB [3072][1024]
  unsigned short* Wtp = (unsigned short*)(ws + 14680064);   //  2 MiB [1024][1024]
  unsigned short* qbf = (unsigned short*)(ws + 16777216);   //  8 MiB fragment-linear
  unsigned short* kbf = (unsigned short*)(ws + 25165824);   //  8 MiB fragment-linear
  unsigned short* vbf = (unsigned short*)(ws + 33554432);   //  8 MiB fragment-linear
  unsigned short* ybf = (unsigned short*)(ws + 41943040);   //  8 MiB [4096][1024]

  k_cvt_x<<<4096, 256, 0, stream>>>(x, xb);
  k_transpose<<<dim3(96, 32), 256, 0, stream>>>(W_attn, Wta, 1024, 3072);
  k_transpose<<<dim3(32, 32), 256, 0, stream>>>(W_proj, Wtp, 1024, 1024);
  k_gemm<0, 1024><<<dim3(32, 24), 256, 0, stream>>>(xb, Wta, b_attn, nullptr, qbf, kbf, vbf);
  k_attn<<<1024, 192, 0, stream>>>(qbf, kbf, vbf, ybf);
  k_gemm<1, 1024><<<dim3(32, 8), 256, 0, stream>>>(ybf, Wtp, b_proj, out, nullptr, nullptr, nullptr);
}

// Round 14
// 114.070 us; speedup vs baseline: 1.5270x; 1.1444x over previous
//
#include <hip/hip_runtime.h>
#include <stdint.h>

#define T_SEQ 2048
#define CDIM 1024
#define NHEAD 16
#define HS 64

typedef __bf16 bf16x8 __attribute__((ext_vector_type(8)));
typedef float f32x4 __attribute__((ext_vector_type(4)));
typedef float f32x16 __attribute__((ext_vector_type(16)));

__device__ __forceinline__ unsigned short f2bf(float f) {
  union { float f; unsigned u; } c; c.f = f;
  unsigned r = c.u + 0x7FFFu + ((c.u >> 16) & 1u);
  return (unsigned short)(r >> 16);
}

__device__ __forceinline__ void gload_lds16(const void* g, void* l) {
  __builtin_amdgcn_global_load_lds((__attribute__((address_space(1))) void*)(g),
                                   (__attribute__((address_space(3))) void*)(l),
                                   16, 0, 0);
}

// Cross-half (lane i <-> lane i^32) exchange via permlane32_swap (pure VALU).
__device__ __forceinline__ float xhalf_other(float x, int hi) {
  union { float f; unsigned u; } c; c.f = x;
  auto r = __builtin_amdgcn_permlane32_swap(c.u, c.u, false, false);
  union { unsigned u; float f; } lo_, hi_;
  lo_.u = (unsigned)r[0]; hi_.u = (unsigned)r[1];
  return hi ? lo_.f : hi_.f;
}

// Fused prepass: [0,4096) x-cvt blocks; [4096,7168) W_attn transpose tiles;
// [7168,8192) W_proj transpose tiles. One launch, concurrent execution.
__global__ __launch_bounds__(256) void k_prep(const float* __restrict__ x,
                                              unsigned short* __restrict__ xb,
                                              const float* __restrict__ Wa,
                                              unsigned short* __restrict__ Wta,
                                              const float* __restrict__ Wp,
                                              unsigned short* __restrict__ Wtp) {
  __shared__ float tile[32][33];
  const int bid = blockIdx.x;
  if (bid < 4096) {
    int i = bid * 256 + threadIdx.x;
    float4 f = reinterpret_cast<const float4*>(x)[i];
    ushort4 u;
    u.x = f2bf(f.x); u.y = f2bf(f.y); u.z = f2bf(f.z); u.w = f2bf(f.w);
    reinterpret_cast<ushort4*>(xb)[i] = u;
    return;
  }
  const float* W; unsigned short* Wt; int N, n0, k0;
  if (bid < 7168) {
    int b2 = bid - 4096; W = Wa; Wt = Wta; N = 3072;
    n0 = (b2 % 96) * 32; k0 = (b2 / 96) * 32;
  } else {
    int b2 = bid - 7168; W = Wp; Wt = Wtp; N = 1024;
    n0 = (b2 & 31) * 32; k0 = (b2 >> 5) * 32;
  }
  int c = threadIdx.x & 31, r0 = threadIdx.x >> 5;
#pragma unroll
  for (int r = r0; r < 32; r += 8) tile[r][c] = W[(size_t)(k0 + r) * N + n0 + c];
  __syncthreads();
#pragma unroll
  for (int r = r0; r < 32; r += 8) Wt[(size_t)(n0 + r) * 1024 + k0 + c] = f2bf(tile[c][r]);
}

// GEMM1: C = A[M][1024] * Bt[N][1024]^T + bias, qkv scatter epilogue in
// FRAGMENT-LINEAR layout (R13): per 64-token tile,
//   K/Q slot = kbk*2048 + dd*512 + l31*16 + hi*8 + j
//   V slot   = db*2048 + t16*512 + l31*16 + hi*8 + j
// K pre-scaled by 1/sqrt(hs)*log2e. 128x128 tile, 4 waves, BK=32.
__global__ __launch_bounds__(256) void k_gemm1(const unsigned short* __restrict__ A,
                                               const unsigned short* __restrict__ Bt,
                                               const float* __restrict__ bias,
                                               unsigned short* __restrict__ qb,
                                               unsigned short* __restrict__ kb,
                                               unsigned short* __restrict__ vb) {
  __shared__ __align__(16) unsigned short Al[128 * 32];
  __shared__ __align__(16) unsigned short Bl[128 * 32];
  const int tid = threadIdx.x;
  const int wave = tid >> 6, lane = tid & 63;
  const int m0 = blockIdx.x * 128, n0 = blockIdx.y * 128;
  const int wr = (wave >> 1) * 64, wc = (wave & 1) * 64;
  const int srow = tid >> 2, scol = (tid & 3) * 8;
  const int ka = (lane >> 4) * 8;
  f32x4 acc[4][4];
#pragma unroll
  for (int m = 0; m < 4; ++m)
#pragma unroll
    for (int n = 0; n < 4; ++n) acc[m][n] = f32x4{0.f, 0.f, 0.f, 0.f};

  for (int k0 = 0; k0 < 1024; k0 += 32) {
#pragma unroll
    for (int r = 0; r < 2; ++r) {
      gload_lds16(A + (size_t)(m0 + r * 64 + srow) * 1024 + k0 + scol,
                  (char*)Al + r * 4096 + wave * 1024);
      gload_lds16(Bt + (size_t)(n0 + r * 64 + srow) * 1024 + k0 + scol,
                  (char*)Bl + r * 4096 + wave * 1024);
    }
    __syncthreads();
    bf16x8 af[4], bfr[4];
#pragma unroll
    for (int m = 0; m < 4; ++m)
      af[m] = *(const bf16x8*)&Al[(wr + m * 16 + (lane & 15)) * 32 + ka];
#pragma unroll
    for (int n = 0; n < 4; ++n)
      bfr[n] = *(const bf16x8*)&Bl[(wc + n * 16 + (lane & 15)) * 32 + ka];
#pragma unroll
    for (int m = 0; m < 4; ++m)
#pragma unroll
      for (int n = 0; n < 4; ++n)
        acc[m][n] = __builtin_amdgcn_mfma_f32_16x16x32_bf16(af[m], bfr[n], acc[m][n], 0, 0, 0);
    __syncthreads();
  }

#pragma unroll
  for (int m = 0; m < 4; ++m)
#pragma unroll
    for (int n = 0; n < 4; ++n)
#pragma unroll
      for (int j = 0; j < 4; ++j) {
        int row = m0 + wr + m * 16 + (lane >> 4) * 4 + j;
        int col = n0 + wc + n * 16 + (lane & 15);
        float v = acc[m][n][j] + bias[col];
        int which = col >> 10;
        int h = (col >> 6) & 15;
        int d = col & 63;
        int b = row >> 11, t = row & (T_SEQ - 1);
        int bh = b * NHEAD + h;
        unsigned short bv = f2bf(which == 1 ? v * 0.18033688f : v);
        size_t tb = ((size_t)bh * 32 + (t >> 6)) * 4096;
        if (which == 2) {
          vb[tb + (d >> 5) * 2048 + ((t >> 4) & 3) * 512 + (d & 31) * 16 +
             ((t >> 3) & 1) * 8 + (t & 7)] = bv;
        } else {
          size_t a = tb + ((t >> 5) & 1) * 2048 + (d >> 4) * 512 + (t & 31) * 16 +
                     ((d >> 3) & 1) * 8 + (d & 7);
          if (which == 0) qb[a] = bv; else kb[a] = bv;
        }
      }
}

// GEMM2: out = A[4096][1024] * Bt[1024][1024]^T + bias, fp32 out.
// 64x128 tile -> grid 64x8 = 512 blocks = 2/CU (the 128x128 version gave 256
// blocks = 1/CU: no co-resident block to fill barrier stalls -- R13 diagnosis).
// 4 waves in 2x2: each wave 32 rows x 64 cols, acc[2][4], 8 MFMAs/K-step.
__global__ __launch_bounds__(256) void k_gemm2(const unsigned short* __restrict__ A,
                                               const unsigned short* __restrict__ Bt,
                                               const float* __restrict__ bias,
                                               float* __restrict__ outF) {
  __shared__ __align__(16) unsigned short Al[64 * 32];
  __shared__ __align__(16) unsigned short Bl[128 * 32];
  const int tid = threadIdx.x;
  const int wave = tid >> 6, lane = tid & 63;
  const int m0 = blockIdx.x * 64, n0 = blockIdx.y * 128;
  const int wr = (wave >> 1) * 32, wc = (wave & 1) * 64;
  const int srow = tid >> 2, scol = (tid & 3) * 8;
  const int ka = (lane >> 4) * 8;
  f32x4 acc[2][4];
#pragma unroll
  for (int m = 0; m < 2; ++m)
#pragma unroll
    for (int n = 0; n < 4; ++n) acc[m][n] = f32x4{0.f, 0.f, 0.f, 0.f};

  for (int k0 = 0; k0 < 1024; k0 += 32) {
    gload_lds16(A + (size_t)(m0 + srow) * 1024 + k0 + scol, (char*)Al + wave * 1024);
#pragma unroll
    for (int r = 0; r < 2; ++r)
      gload_lds16(Bt + (size_t)(n0 + r * 64 + srow) * 1024 + k0 + scol,
                  (char*)Bl + r * 4096 + wave * 1024);
    __syncthreads();
    bf16x8 af[2], bfr[4];
#pragma unroll
    for (int m = 0; m < 2; ++m)
      af[m] = *(const bf16x8*)&Al[(wr + m * 16 + (lane & 15)) * 32 + ka];
#pragma unroll
    for (int n = 0; n < 4; ++n)
      bfr[n] = *(const bf16x8*)&Bl[(wc + n * 16 + (lane & 15)) * 32 + ka];
#pragma unroll
    for (int m = 0; m < 2; ++m)
#pragma unroll
      for (int n = 0; n < 4; ++n)
        acc[m][n] = __builtin_amdgcn_mfma_f32_16x16x32_bf16(af[m], bfr[n], acc[m][n], 0, 0, 0);
    __syncthreads();
  }

#pragma unroll
  for (int m = 0; m < 2; ++m)
#pragma unroll
    for (int n = 0; n < 4; ++n)
#pragma unroll
      for (int j = 0; j < 4; ++j) {
        int row = m0 + wr + m * 16 + (lane >> 4) * 4 + j;
        int col = n0 + wc + n * 16 + (lane & 15);
        outF[(size_t)row * CDIM + col] = acc[m][n][j] + bias[col];
      }
}

// Flash attention: R13 structure widened to KV-SPLIT-4 (256 thr = 4 waves).
// Serial chain 11 -> 8.25 tiles/wave; supply 3072 -> 4096 waves (4/SIMD).
// 32x32 lane-local softmax, pipelined QK, permlane reduces, defer-max,
// fragment-linear Q/K/V (1KB dense wave loads), balanced pairs (63-p, p).
// 4-way LDS merge twice per block. LDS 35.3KB -> 4 blocks/CU.
#define MOSTR 67
__global__ __launch_bounds__(256) void k_attn(const unsigned short* __restrict__ qb,
                                              const unsigned short* __restrict__ kb,
                                              const unsigned short* __restrict__ vb,
                                              unsigned short* __restrict__ yb) {
  __shared__ float Mo[4 * 32 * MOSTR];   // 34304 B partial O^T
  __shared__ float Lml[4][2][32];        // partial m, l per q
  // rid -> (xcd, bh, pair). 8 XCDs x 4 bh x 32 pairs = 1024 blocks.
  const int rid = blockIdx.x;
  const int xcd = rid & 7, i = rid >> 3;       // i in 0..127
  const int bh = xcd * 4 + (i & 3);
  const int p = i >> 2;                        // 0..31
  const int wave = threadIdx.x >> 6;           // 0..3
  const int lane = threadIdx.x & 63;
  const int l31 = lane & 31, hi = lane >> 5;
  const unsigned short* qh = qb + (size_t)bh * T_SEQ * HS;
  const unsigned short* kh = kb + (size_t)bh * T_SEQ * HS;
  const unsigned short* vh = vb + (size_t)bh * T_SEQ * HS;
  const int b = bh >> 4, h = bh & 15;
  const int lbase = l31 * 16 + hi * 8;         // per-lane offset within a 512-slab

  for (int grp = 0; grp < 2; ++grp) {
    const int g = grp ? p : 63 - p;
    const int q0 = g * 32;
    const int nkt = (q0 >> 6) + 1;

    // Q B-frags (fragment-linear): col=q=l31, k(d) = dd*16 + hi*8 + {0..7}
    const size_t qbase = (size_t)(g >> 1) * 4096 + (size_t)(g & 1) * 2048;
    bf16x8 qf[4];
#pragma unroll
    for (int dd = 0; dd < 4; ++dd)
      qf[dd] = *(const bf16x8*)&qh[qbase + dd * 512 + lbase];

    f32x16 o2[2];                 // O^T acc: col=q=l31, rows d = db*32 + rowpat
#pragma unroll
    for (int db = 0; db < 2; ++db)
#pragma unroll
      for (int e = 0; e < 16; ++e) o2[db][e] = 0.f;
    float Mx = -INFINITY, Ls = 0.f;

    // prologue: K A-frags + QK of this wave's first tile (index < 32, in-bounds)
    bf16x8 kf[2][4];
#pragma unroll
    for (int kbk = 0; kbk < 2; ++kbk)
#pragma unroll
      for (int dd = 0; dd < 4; ++dd)
        kf[kbk][dd] = *(const bf16x8*)&kh[(size_t)wave * 4096 + kbk * 2048 + dd * 512 + lbase];
    f32x16 s[2];
#pragma unroll
    for (int kbk = 0; kbk < 2; ++kbk) {
      f32x16 z;
#pragma unroll
      for (int e = 0; e < 16; ++e) z[e] = 0.f;
#pragma unroll
      for (int dd = 0; dd < 4; ++dd)
        z = __builtin_amdgcn_mfma_f32_32x32x16_bf16(kf[kbk][dd], qf[dd], z, 0, 0, 0);
      s[kbk] = z;
    }

    for (int kt = wave; kt < nkt; kt += 4) {
      const int kvb = kt * 64;
      const bool more = (kt + 4 < nkt);

      // issue K loads for tile kt+4 (kf regs free: QK(kt) already computed)
      if (more) {
#pragma unroll
        for (int kbk = 0; kbk < 2; ++kbk)
#pragma unroll
          for (int dd = 0; dd < 4; ++dd)
            kf[kbk][dd] = *(const bf16x8*)&kh[(size_t)(kt + 4) * 4096 + kbk * 2048 + dd * 512 + lbase];
      }
      // issue V loads for THIS tile (consumed after softmax -> latency hidden)
      bf16x8 vf[2][4];
#pragma unroll
      for (int db = 0; db < 2; ++db)
#pragma unroll
        for (int t16 = 0; t16 < 4; ++t16)
          vf[db][t16] = *(const bf16x8*)&vh[(size_t)kt * 4096 + db * 2048 + t16 * 512 + lbase];

      // causal mask (only the group's last tile has kvb+63 > q0)
      if (kvb + 63 > q0) {
        const int qg = q0 + l31;
#pragma unroll
        for (int kbk = 0; kbk < 2; ++kbk)
#pragma unroll
          for (int r = 0; r < 16; ++r) {
            const int key = kvb + kbk * 32 + (r & 3) + 8 * (r >> 2) + 4 * hi;
            if (key > qg) s[kbk][r] = -3.0e38f;
          }
      }

      // row max: in-register tree (31 fmax) + permlane cross-half
      f32x16 tm;
#pragma unroll
      for (int e = 0; e < 16; ++e) tm[e] = fmaxf(s[0][e], s[1][e]);
      float m8[8];
#pragma unroll
      for (int e = 0; e < 8; ++e) m8[e] = fmaxf(tm[e], tm[e + 8]);
      float m4a = fmaxf(m8[0], m8[4]), m4b = fmaxf(m8[1], m8[5]);
      float m4c = fmaxf(m8[2], m8[6]), m4d = fmaxf(m8[3], m8[7]);
      float mx = fmaxf(fmaxf(m4a, m4b), fmaxf(m4c, m4d));
      mx = fmaxf(mx, xhalf_other(mx, hi));

      // defer-max (T13): skip rescale while max growth <= 8 (P <= 2^8).
      if (!__all(mx <= Mx + 8.f)) {
        const float newM = fmaxf(Mx, mx);
        const float alpha = __builtin_exp2f(Mx - newM);
        Mx = newM;
        Ls *= alpha;
#pragma unroll
        for (int db = 0; db < 2; ++db)
#pragma unroll
          for (int e = 0; e < 16; ++e) o2[db][e] *= alpha;
      }

      // p = exp2(s - Mx) in place; row sum (31 adds) + permlane cross-half
#pragma unroll
      for (int kbk = 0; kbk < 2; ++kbk)
#pragma unroll
        for (int r = 0; r < 16; ++r) s[kbk][r] = __builtin_exp2f(s[kbk][r] - Mx);
      f32x16 ts;
#pragma unroll
      for (int e = 0; e < 16; ++e) ts[e] = s[0][e] + s[1][e];
      float s8[8];
#pragma unroll
      for (int e = 0; e < 8; ++e) s8[e] = ts[e] + ts[e + 8];
      float rs = ((s8[0] + s8[1]) + (s8[2] + s8[3])) + ((s8[4] + s8[5]) + (s8[6] + s8[7]));
      rs += xhalf_other(rs, hi);
      Ls += rs;

      // pack P: W[kb][rg] = 2 words (4 bf16, rows 8rg+4hi+{0..3})
      unsigned W0[2][4], W1[2][4];
#pragma unroll
      for (int kbk = 0; kbk < 2; ++kbk)
#pragma unroll
        for (int rg = 0; rg < 4; ++rg) {
          unsigned lo, hiw;
          asm("v_cvt_pk_bf16_f32 %0, %1, %2" : "=v"(lo) : "v"(s[kbk][4 * rg + 0]), "v"(s[kbk][4 * rg + 1]));
          asm("v_cvt_pk_bf16_f32 %0, %1, %2" : "=v"(hiw) : "v"(s[kbk][4 * rg + 2]), "v"(s[kbk][4 * rg + 3]));
          W0[kbk][rg] = lo; W1[kbk][rg] = hiw;
        }

      // build PV B-frags (P^T: col=q=l31, k = t16*16 + hi*8 + {0..7}) with
      // 8 permlane32_swap: swap(W[rgA].w, W[rgB].w) -> both frag halves.
      bf16x8 pf[4];
#pragma unroll
      for (int t16 = 0; t16 < 4; ++t16) {
        const int kbk = t16 >> 1, par = t16 & 1;
        unsigned a0 = W0[kbk][2 * par], b0 = W0[kbk][2 * par + 1];
        unsigned a1 = W1[kbk][2 * par], b1 = W1[kbk][2 * par + 1];
        auto r0 = __builtin_amdgcn_permlane32_swap(a0, b0, false, false);
        auto r1 = __builtin_amdgcn_permlane32_swap(a1, b1, false, false);
        union { unsigned u[4]; bf16x8 v; } cv;
        cv.u[0] = (unsigned)r0[0]; cv.u[1] = (unsigned)r1[0];
        cv.u[2] = (unsigned)r0[1]; cv.u[3] = (unsigned)r1[1];
        pf[t16] = cv.v;
      }

      // PV: O^T[d][q] += V[d][k] * P^T[k][q]
#pragma unroll
      for (int db = 0; db < 2; ++db)
#pragma unroll
        for (int t16 = 0; t16 < 4; ++t16)
          o2[db] = __builtin_amdgcn_mfma_f32_32x32x16_bf16(vf[db][t16], pf[t16], o2[db], 0, 0, 0);

      // QK for tile kt+4 at iteration END (kf loads had softmax+PV to land).
      if (more) {
#pragma unroll
        for (int kbk = 0; kbk < 2; ++kbk) {
          f32x16 z;
#pragma unroll
          for (int e = 0; e < 16; ++e) z[e] = 0.f;
#pragma unroll
          for (int dd = 0; dd < 4; ++dd)
            z = __builtin_amdgcn_mfma_f32_32x32x16_bf16(kf[kbk][dd], qf[dd], z, 0, 0, 0);
          s[kbk] = z;
        }
      }
    }

    // ---- publish partials ----
    if (hi == 0) {
      Lml[wave][0][l31] = Mx;
      Lml[wave][1][l31] = Ls;
    }
#pragma unroll
    for (int db = 0; db < 2; ++db)
#pragma unroll
      for (int r = 0; r < 16; ++r)
        Mo[wave * 32 * MOSTR + l31 * MOSTR + db * 32 + (r & 3) + 8 * (r >> 2) + 4 * hi] = o2[db][r];
    __syncthreads();

    // ---- distributed 4-way merge + store: 256 chunks of 8 cols ----
    {
      const int c = threadIdx.x;
      const int rl = c >> 3, c0 = (c & 7) * 8;
      const float m0 = Lml[0][0][rl], m1 = Lml[1][0][rl], m2 = Lml[2][0][rl], m3 = Lml[3][0][rl];
      const float l0 = Lml[0][1][rl], l1 = Lml[1][1][rl], l2 = Lml[2][1][rl], l3 = Lml[3][1][rl];
      const float M = fmaxf(fmaxf(m0, m1), fmaxf(m2, m3));
      const float a0 = __builtin_exp2f(m0 - M);
      const float a1 = __builtin_exp2f(m1 - M);
      const float a2 = __builtin_exp2f(m2 - M);
      const float a3 = __builtin_exp2f(m3 - M);
      const float inv = 1.0f / (a0 * l0 + a1 * l1 + a2 * l2 + a3 * l3);
      const float* O0 = &Mo[rl * MOSTR + c0];
      const float* O1 = O0 + 32 * MOSTR;
      const float* O2 = O0 + 64 * MOSTR;
      const float* O3 = O0 + 96 * MOSTR;
      unsigned pk[4];
#pragma unroll
      for (int e = 0; e < 4; ++e) {
        float va = (a0 * O0[2 * e] + a1 * O1[2 * e] + a2 * O2[2 * e] + a3 * O3[2 * e]) * inv;
        float vb2 = (a0 * O0[2 * e + 1] + a1 * O1[2 * e + 1] + a2 * O2[2 * e + 1] + a3 * O3[2 * e + 1]) * inv;
        pk[e] = (unsigned)f2bf(va) | ((unsigned)f2bf(vb2) << 16);
      }
      uint4 u; u.x = pk[0]; u.y = pk[1]; u.z = pk[2]; u.w = pk[3];
      *(uint4*)&yb[(size_t)(b * T_SEQ + q0 + rl) * CDIM + h * 64 + c0] = u;
    }
    __syncthreads();  // Mo reused by next group
  }
}

extern "C" void kernel_launch(void* const* d_in, const int* in_sizes, int n_in,
                              void* d_out, int out_size, void* d_ws, size_t ws_size,
                              hipStream_t stream) {
  (void)in_sizes; (void)n_in; (void)out_size; (void)ws_size;
  const float* x      = (const float*)d_in[0];
  const float* W_attn = (const float*)d_in[1];
  const float* b_attn = (const float*)d_in[2];
  const float* W_proj = (const float*)d_in[3];
  const float* b_proj = (const float*)d_in[4];
  float* out = (float*)d_out;
  char* ws = (char*)d_ws;

  unsigned short* xb  = (unsigned short*)(ws);              //  8 MiB [4096][1024]
  unsigned short* Wta = (unsigned short*)(ws + 8388608);    //  6 MiB [3072][1024]
  unsigned short* Wtp = (unsigned short*)(ws + 14680064);   //  2 MiB [1024][1024]
  unsigned short* qbf = (unsigned short*)(ws + 16777216);   //  8 MiB fragment-linear
  unsigned short* kbf = (unsigned short*)(ws + 25165824);   //  8 MiB fragment-linear
  unsigned short* vbf = (unsigned short*)(ws + 33554432);   //  8 MiB fragment-linear
  unsigned short* ybf = (unsigned short*)(ws + 41943040);   //  8 MiB [4096][1024]

  k_prep<<<8192, 256, 0, stream>>>(x, xb, W_attn, Wta, W_proj, Wtp);
  k_gemm1<<<dim3(32, 24), 256, 0, stream>>>(xb, Wta, b_attn, qbf, kbf, vbf);
  k_attn<<<1024, 256, 0, stream>>>(qbf, kbf, vbf, ybf);
  k_gemm2<<<dim3(64, 8), 256, 0, stream>>>(ybf, Wtp, b_proj, out);
}